// Round 2
// baseline (1313.802 us; speedup 1.0000x reference)
//
#include <hip/hip_runtime.h>
#include <hip/hip_bf16.h>

typedef __hip_bfloat16 bf16;
typedef __attribute__((ext_vector_type(8))) short bfrag8;   // 8 bf16 (4 VGPR) MFMA A/B frag
typedef __attribute__((ext_vector_type(4))) float facc4;    // MFMA C/D frag

#define AS1C const __attribute__((address_space(1))) void
#define AS3  __attribute__((address_space(3))) void

__device__ __forceinline__ void gload_lds16(const void* src, void* dst) {
    __builtin_amdgcn_global_load_lds((AS1C*)src, (AS3*)dst, 16, 0, 0);
}

// ---------------- merged prep kernel: pe | xin | wemb | whead ----------------
__global__ void prep_kernel(const float* __restrict__ input, const float* __restrict__ targets,
                            const float* __restrict__ sos, const float* __restrict__ W_emb,
                            const float* __restrict__ Wm, const float* __restrict__ Wpi_m,
                            const float* __restrict__ Wmu_m, const float* __restrict__ Wsg_m,
                            const float* __restrict__ Wpi_v, const float* __restrict__ Wmu_v,
                            const float* __restrict__ Wsg_v,
                            const float* __restrict__ bm, const float* __restrict__ bpi_m,
                            const float* __restrict__ bmu_m, const float* __restrict__ bsg_m,
                            const float* __restrict__ bpi_v, const float* __restrict__ bmu_v,
                            const float* __restrict__ bsg_v,
                            float* __restrict__ pe, bf16* __restrict__ xin,
                            bf16* __restrict__ wemb, bf16* __restrict__ whead,
                            float* __restrict__ bhead) {
    int bid = blockIdx.x;
    if (bid < 512) {                                     // pe [128][1024]
        int idx = bid * 256 + threadIdx.x;
        int s = idx >> 10, c = idx & 1023;
        int i = c >> 1;
        float div = expf(-9.210340371976184f * (float)(2 * i) * (1.f / 1024.f));
        float a = (float)s * div;
        pe[idx] = (c & 1) ? cosf(a) : sinf(a);
    } else if (bid < 512 + 4096) {                       // xin row (b*128+s), pad K->576
        int row = bid - 512;
        int b = row >> 7, s = row & 127;
        for (int c = threadIdx.x; c < 576; c += 256) {
            float v = 0.f;
            if (c < 512) v = input[b * 512 + c];
            else if (c < 545) {
                int j = c - 512;
                v = (s == 0) ? sos[j] : targets[((size_t)b * 127 + (s - 1)) * 33 + j];
            }
            xin[(size_t)row * 576 + c] = __float2bfloat16(v);
        }
    } else if (bid < 512 + 4096 + 1024) {                // wemb row, pad 545->576
        int row = bid - (512 + 4096);
        for (int c = threadIdx.x; c < 576; c += 256)
            wemb[(size_t)row * 576 + c] = __float2bfloat16(c < 545 ? W_emb[(size_t)row * 545 + c] : 0.f);
    } else {                                             // whead row (640 = 529 real + pad)
        int r = bid - (512 + 4096 + 1024);
        const float* wsrc = nullptr; const float* bsrc = nullptr; int off = 0;
        if (r == 0)        { wsrc = Wm;    bsrc = bm;    off = 0; }
        else if (r < 9)    { wsrc = Wpi_m; bsrc = bpi_m; off = r - 1; }
        else if (r < 137)  { wsrc = Wmu_m; bsrc = bmu_m; off = r - 9; }
        else if (r < 265)  { wsrc = Wsg_m; bsrc = bsg_m; off = r - 137; }
        else if (r < 273)  { wsrc = Wpi_v; bsrc = bpi_v; off = r - 265; }
        else if (r < 401)  { wsrc = Wmu_v; bsrc = bmu_v; off = r - 273; }
        else if (r < 529)  { wsrc = Wsg_v; bsrc = bsg_v; off = r - 401; }
        for (int c = threadIdx.x; c < 1024; c += 256)
            whead[(size_t)r * 1024 + c] = __float2bfloat16(wsrc ? wsrc[(size_t)off * 1024 + c] : 0.f);
        if (threadIdx.x == 0 && wsrc) bhead[r] = bsrc[off];
    }
}

// ---------------- one-shot weight conversion for ALL layers ----------------
// per-layer float4 counts: Wqkv 786432 | Wo 262144 | W1 262144 | W2 262144 = 1572864
__global__ void cvt_all_kernel(const float* __restrict__ Wqkv, const float* __restrict__ Wo,
                               const float* __restrict__ W1, const float* __restrict__ W2,
                               bf16* __restrict__ wqb, bf16* __restrict__ wob,
                               bf16* __restrict__ w1b, bf16* __restrict__ w2b) {
    const int NTOT = 9437184;                            // 6 layers * 1572864
    for (int i = blockIdx.x * 256 + threadIdx.x; i < NTOT; i += gridDim.x * 256) {
        int l = i / 1572864;
        int r = i - l * 1572864;
        const float* src; bf16* dst; size_t o;
        if (r < 786432)       { src = Wqkv + (size_t)l * 3145728; dst = wqb + (size_t)l * 3145728; o = (size_t)r * 4; }
        else if (r < 1048576) { src = Wo   + (size_t)l * 1048576; dst = wob + (size_t)l * 1048576; o = (size_t)(r - 786432) * 4; }
        else if (r < 1310720) { src = W1   + (size_t)l * 1048576; dst = w1b + (size_t)l * 1048576; o = (size_t)(r - 1048576) * 4; }
        else                  { src = W2   + (size_t)l * 1048576; dst = w2b + (size_t)l * 1048576; o = (size_t)(r - 1310720) * 4; }
        float4 v = *(const float4*)(src + o);
        dst[o + 0] = __float2bfloat16(v.x);
        dst[o + 1] = __float2bfloat16(v.y);
        dst[o + 2] = __float2bfloat16(v.z);
        dst[o + 3] = __float2bfloat16(v.w);
    }
}

// ---------------- main GEMM: C[M,N] = A[M,K] @ B[N,K]^T (+epilogue) ----------------
// 128x128 tile, BK=64, 4 waves (each 64x64 of 16x16x32 bf16 MFMA).
// T3-minimum prefetch: double-buffered LDS; STAGE(k+1) issued BEFORE compute(k)
// so global->LDS latency hides under MFMA; one barrier per k-tile.
// LDS XOR-swizzle (byte ^ ((row&7)<<4)) via pre-swizzled global source (linear LDS dest).
// EPI: 0 bias->bf16 | 1 bias+relu->bf16 | 2 bias+res->f32 | 3 bias->f32 | 4 bias+pe->f32+bf16
template<int EPI>
__global__ __launch_bounds__(256) void gemm_bt(
    const bf16* __restrict__ A, const bf16* __restrict__ Bw,
    float* __restrict__ Cf, bf16* __restrict__ Cb,
    const float* __restrict__ bias, const float* __restrict__ res, const float* __restrict__ pe,
    int M, int N, int K, int lda, int ldb, int ldc, long long Az, long long Cz)
{
    __shared__ __align__(16) bf16 sA[2][128 * 64];
    __shared__ __align__(16) bf16 sB[2][128 * 64];
    const int t = threadIdx.x;
    const int w = t >> 6, la = t & 63;
    const int wm = (w >> 1) * 64, wn = (w & 1) * 64;
    const int m0 = blockIdx.y * 128, n0 = blockIdx.x * 128;
    const int z = blockIdx.z;
    A += (long long)z * Az;

    // per-thread staging geometry (8 chunks of 16B per 128B row)
    const int c0 = w * 64 + la;
    facc4 zero4 = {0.f, 0.f, 0.f, 0.f};
    facc4 acc[4][4];
#pragma unroll
    for (int mi = 0; mi < 4; ++mi)
#pragma unroll
        for (int ni = 0; ni < 4; ++ni) acc[mi][ni] = zero4;

    auto stage = [&](int buf, int kt) {
#pragma unroll
        for (int i = 0; i < 4; ++i) {
            int c = i * 256 + c0;
            int r = c >> 3;
            int bc = ((c & 7) * 16) ^ ((r & 7) << 4);   // pre-swizzled source byte col
            gload_lds16(A + (size_t)(m0 + r) * lda + kt + (bc >> 1),
                        (char*)sA[buf] + (size_t)(i * 256 + c0) * 16);
            gload_lds16(Bw + (size_t)(n0 + r) * ldb + kt + (bc >> 1),
                        (char*)sB[buf] + (size_t)(i * 256 + c0) * 16);
        }
    };

    const int nk = K >> 6;
    stage(0, 0);
    __syncthreads();
    int cur = 0;
    for (int kt = 0; kt < nk; ++kt) {
        if (kt + 1 < nk) stage(cur ^ 1, (kt + 1) << 6);
#pragma unroll
        for (int ks = 0; ks < 2; ++ks) {
            bfrag8 af[4], bfv[4];
            const int koffb = (ks * 32 + (la >> 4) * 8) * 2;
#pragma unroll
            for (int i = 0; i < 4; ++i) {
                int rowa = wm + i * 16 + (la & 15);
                af[i] = *(const bfrag8*)((const char*)sA[cur] + rowa * 128 + (koffb ^ ((rowa & 7) << 4)));
                int rowb = wn + i * 16 + (la & 15);
                bfv[i] = *(const bfrag8*)((const char*)sB[cur] + rowb * 128 + (koffb ^ ((rowb & 7) << 4)));
            }
#pragma unroll
            for (int mi = 0; mi < 4; ++mi)
#pragma unroll
                for (int ni = 0; ni < 4; ++ni)
                    acc[mi][ni] = __builtin_amdgcn_mfma_f32_16x16x32_bf16(af[mi], bfv[ni], acc[mi][ni], 0, 0, 0);
        }
        __syncthreads();        // drains vmcnt (stage done) + lgkm; frees cur for next stage
        cur ^= 1;
    }
    // epilogue
#pragma unroll
    for (int mi = 0; mi < 4; ++mi) {
#pragma unroll
        for (int ni = 0; ni < 4; ++ni) {
            int col = n0 + wn + ni * 16 + (la & 15);
            if (col >= N) continue;
            float bv = bias[col];
#pragma unroll
            for (int j = 0; j < 4; ++j) {
                int row = m0 + wm + mi * 16 + (la >> 4) * 4 + j;
                if (row >= M) continue;
                float v = acc[mi][ni][j] + bv;
                size_t cidx = (size_t)z * Cz + (size_t)row * ldc + col;
                if constexpr (EPI == 0) {
                    Cb[cidx] = __float2bfloat16(v);
                } else if constexpr (EPI == 1) {
                    Cb[cidx] = __float2bfloat16(v > 0.f ? v : 0.f);
                } else if constexpr (EPI == 2) {
                    Cf[cidx] = v + res[(size_t)row * ldc + col];
                } else if constexpr (EPI == 3) {
                    Cf[cidx] = v;
                } else {
                    float u = v + pe[(size_t)(row & 127) * 1024 + col];
                    Cf[cidx] = u;
                    Cb[cidx] = __float2bfloat16(u);
                }
            }
        }
    }
}

// ---------------- fused attention: one block per (b,h) ----------------
// S=128, D=64. QK^T -> causal softmax (fp32 math, bf16 storage) -> PV. 64KB LDS.
__global__ __launch_bounds__(256) void attn_fused(const bf16* __restrict__ qkv, bf16* __restrict__ obf)
{
    __shared__ __align__(16) char lds[65536];
    char* sQ  = lds;            // [128] rows x 128B, swizzled
    char* sK  = lds + 16384;    // [128] rows x 128B
    char* sS  = lds + 32768;    // [128] rows x 256B bf16 (scores, then P)
    char* sVT = lds;            // [64] rows x 256B (V transposed), overlaps sQ

    const int t = threadIdx.x, w = t >> 6, la = t & 63;
    const int b = blockIdx.x >> 4, h = blockIdx.x & 15;
    const size_t base = (size_t)b * 128 * 3072 + (size_t)h * 64;

    // phase 1: stage Q, K (swizzled via pre-swizzled source)
#pragma unroll
    for (int i = 0; i < 4; ++i) {
        int c = i * 256 + w * 64 + la;
        int r = c >> 3;
        int bc = ((c & 7) * 16) ^ ((r & 7) << 4);
        gload_lds16(qkv + base + (size_t)r * 3072 + (bc >> 1),
                    sQ + (size_t)(i * 256 + w * 64) * 16);
        gload_lds16(qkv + base + 1024 + (size_t)r * 3072 + (bc >> 1),
                    sK + (size_t)(i * 256 + w * 64) * 16);
    }
    __syncthreads();

    // phase 2: S = Q K^T * 0.125
    const int wm = (w >> 1) * 64, wn = (w & 1) * 64;
    facc4 zero4 = {0.f, 0.f, 0.f, 0.f};
    {
        facc4 acc[4][4];
#pragma unroll
        for (int mi = 0; mi < 4; ++mi)
#pragma unroll
            for (int ni = 0; ni < 4; ++ni) acc[mi][ni] = zero4;
#pragma unroll
        for (int ks = 0; ks < 2; ++ks) {
            bfrag8 af[4], bfv[4];
            const int koffb = (ks * 32 + (la >> 4) * 8) * 2;
#pragma unroll
            for (int i = 0; i < 4; ++i) {
                int rowa = wm + i * 16 + (la & 15);
                af[i] = *(const bfrag8*)(sQ + rowa * 128 + (koffb ^ ((rowa & 7) << 4)));
                int rowb = wn + i * 16 + (la & 15);
                bfv[i] = *(const bfrag8*)(sK + rowb * 128 + (koffb ^ ((rowb & 7) << 4)));
            }
#pragma unroll
            for (int mi = 0; mi < 4; ++mi)
#pragma unroll
                for (int ni = 0; ni < 4; ++ni)
                    acc[mi][ni] = __builtin_amdgcn_mfma_f32_16x16x32_bf16(af[mi], bfv[ni], acc[mi][ni], 0, 0, 0);
        }
#pragma unroll
        for (int mi = 0; mi < 4; ++mi)
#pragma unroll
            for (int ni = 0; ni < 4; ++ni)
#pragma unroll
                for (int j = 0; j < 4; ++j) {
                    int row = wm + mi * 16 + (la >> 4) * 4 + j;
                    int col = wn + ni * 16 + (la & 15);
                    *(bf16*)(sS + row * 256 + ((2 * col) ^ ((row & 7) << 4))) =
                        __float2bfloat16(acc[mi][ni][j] * 0.125f);
                }
    }
    __syncthreads();

    // phase 3a: stage V transposed into sVT (sQ space, free now)
#pragma unroll
    for (int i = 0; i < 4; ++i) {
        int c = i * 256 + t;
        int r = c >> 3;             // key index s'
        int d0 = (c & 7) * 8;
        bfrag8 vv = *(const bfrag8*)(qkv + base + 2048 + (size_t)r * 3072 + d0);
#pragma unroll
        for (int j = 0; j < 8; ++j) {
            int d = d0 + j;
            *(short*)(sVT + d * 256 + ((2 * r) ^ ((d & 7) << 4))) = vv[j];
        }
    }
    // phase 3b: causal softmax, in place on sS (wave w owns rows w*32..w*32+31)
    for (int ri = 0; ri < 32; ++ri) {
        int r = w * 32 + ri;
        int c1 = la, c2 = la + 64;
        float v1 = (c1 <= r) ? __bfloat162float(*(const bf16*)(sS + r * 256 + ((2 * c1) ^ ((r & 7) << 4)))) : -1e30f;
        float v2 = (c2 <= r) ? __bfloat162float(*(const bf16*)(sS + r * 256 + ((2 * c2) ^ ((r & 7) << 4)))) : -1e30f;
        float mx = fmaxf(v1, v2);
#pragma unroll
        for (int off = 32; off; off >>= 1) mx = fmaxf(mx, __shfl_xor(mx, off));
        float e1 = (c1 <= r) ? __expf(v1 - mx) : 0.f;
        float e2 = (c2 <= r) ? __expf(v2 - mx) : 0.f;
        float sm = e1 + e2;
#pragma unroll
        for (int off = 32; off; off >>= 1) sm += __shfl_xor(sm, off);
        float inv = 1.f / sm;
        *(bf16*)(sS + r * 256 + ((2 * c1) ^ ((r & 7) << 4))) = __float2bfloat16(e1 * inv);
        *(bf16*)(sS + r * 256 + ((2 * c2) ^ ((r & 7) << 4))) = __float2bfloat16(e2 * inv);
    }
    __syncthreads();

    // phase 4: O = P V  (wave tile 64M x 32N, K=128)
    const int wm2 = (w >> 1) * 64, wn2 = (w & 1) * 32;
    facc4 a2[4][2];
#pragma unroll
    for (int mi = 0; mi < 4; ++mi) { a2[mi][0] = zero4; a2[mi][1] = zero4; }
#pragma unroll
    for (int ks = 0; ks < 4; ++ks) {
        bfrag8 pa[4], vb[2];
        const int koffb = (ks * 32 + (la >> 4) * 8) * 2;
#pragma unroll
        for (int mi = 0; mi < 4; ++mi) {
            int rowa = wm2 + mi * 16 + (la & 15);
            pa[mi] = *(const bfrag8*)(sS + rowa * 256 + (koffb ^ ((rowa & 7) << 4)));
        }
#pragma unroll
        for (int ni = 0; ni < 2; ++ni) {
            int rowb = wn2 + ni * 16 + (la & 15);
            vb[ni] = *(const bfrag8*)(sVT + rowb * 256 + (koffb ^ ((rowb & 7) << 4)));
        }
#pragma unroll
        for (int mi = 0; mi < 4; ++mi)
#pragma unroll
            for (int ni = 0; ni < 2; ++ni)
                a2[mi][ni] = __builtin_amdgcn_mfma_f32_16x16x32_bf16(pa[mi], vb[ni], a2[mi][ni], 0, 0, 0);
    }
#pragma unroll
    for (int mi = 0; mi < 4; ++mi)
#pragma unroll
        for (int ni = 0; ni < 2; ++ni)
#pragma unroll
            for (int j = 0; j < 4; ++j) {
                int s = wm2 + mi * 16 + (la >> 4) * 4 + j;
                int d = wn2 + ni * 16 + (la & 15);
                obf[((size_t)(b * 128 + s)) * 1024 + h * 64 + d] = __float2bfloat16(a2[mi][ni][j]);
            }
}

// ---------------- LayerNorm (one block per row of 1024) ----------------
__global__ __launch_bounds__(256) void ln_kernel(const float* __restrict__ in, const float* __restrict__ g,
                                                 const float* __restrict__ be,
                                                 float* __restrict__ outf, bf16* __restrict__ outb)
{
    const int row = blockIdx.x, t = threadIdx.x;
    const float* x = in + (size_t)row * 1024;
    float4 v = *(const float4*)(x + t * 4);
    float s = v.x + v.y + v.z + v.w;
    float q = v.x * v.x + v.y * v.y + v.z * v.z + v.w * v.w;
#pragma unroll
    for (int off = 32; off; off >>= 1) {
        s += __shfl_xor(s, off);
        q += __shfl_xor(q, off);
    }
    __shared__ float ssum[4], sqs[4];
    if ((t & 63) == 0) { ssum[t >> 6] = s; sqs[t >> 6] = q; }
    __syncthreads();
    s = ssum[0] + ssum[1] + ssum[2] + ssum[3];
    q = sqs[0] + sqs[1] + sqs[2] + sqs[3];
    float mean = s * (1.f / 1024.f);
    float var = q * (1.f / 1024.f) - mean * mean;
    float rstd = rsqrtf(var + 1e-5f);
    float4 gv = *(const float4*)(g + t * 4);
    float4 bv = *(const float4*)(be + t * 4);
    size_t o = (size_t)row * 1024 + t * 4;
    float o0 = (v.x - mean) * rstd * gv.x + bv.x;
    float o1 = (v.y - mean) * rstd * gv.y + bv.y;
    float o2 = (v.z - mean) * rstd * gv.z + bv.z;
    float o3 = (v.w - mean) * rstd * gv.w + bv.w;
    outf[o + 0] = o0; outf[o + 1] = o1; outf[o + 2] = o2; outf[o + 3] = o3;
    outb[o + 0] = __float2bfloat16(o0); outb[o + 1] = __float2bfloat16(o1);
    outb[o + 2] = __float2bfloat16(o2); outb[o + 3] = __float2bfloat16(o3);
}

// ---------------- MDN finalize / scatter ----------------
__global__ void finalize_kernel(const float* __restrict__ hout, float* __restrict__ out) {
    const size_t O_PI_M = 0, O_MU_M = 32512, O_VAR_M = 552704, O_PI_V = 1072896,
                 O_MU_V = 1105408, O_VAR_V = 1625600, O_MASK = 2145792;
    int rm = blockIdx.x;                    // b*127+m, 4064 rows
    const float* hrow = hout + (size_t)rm * 529;
    int t = threadIdx.x;
    if (t < 128) {
        out[O_MU_M  + (size_t)rm * 128 + t] = hrow[9 + t];
        out[O_VAR_M + (size_t)rm * 128 + t] = expf(hrow[137 + t]);
        out[O_MU_V  + (size_t)rm * 128 + t] = hrow[273 + t];
        out[O_VAR_V + (size_t)rm * 128 + t] = expf(hrow[401 + t]);
    } else if (t == 128) {
        out[O_MASK + rm] = hrow[0];
    } else if (t == 129 || t == 130) {
        int boff = (t == 129) ? 1 : 265;
        size_t oo = ((t == 129) ? O_PI_M : O_PI_V) + (size_t)rm * 8;
        float v[8], mx = -1e30f;
#pragma unroll
        for (int j = 0; j < 8; ++j) { v[j] = hrow[boff + j]; mx = fmaxf(mx, v[j]); }
        float sm = 0.f;
#pragma unroll
        for (int j = 0; j < 8; ++j) { v[j] = expf(v[j] - mx); sm += v[j]; }
        float inv = 1.f / sm;
#pragma unroll
        for (int j = 0; j < 8; ++j) out[oo + j] = v[j] * inv;
    }
}

// ---------------- launcher ----------------
extern "C" void kernel_launch(void* const* d_in, const int* in_sizes, int n_in,
                              void* d_out, int out_size, void* d_ws, size_t ws_size,
                              hipStream_t stream) {
    (void)in_sizes; (void)n_in; (void)out_size; (void)ws_size;
    const float* input   = (const float*)d_in[0];
    const float* targets = (const float*)d_in[1];
    const float* W_emb   = (const float*)d_in[2];
    const float* b_emb   = (const float*)d_in[3];
    const float* sos     = (const float*)d_in[4];
    const float* Wqkv    = (const float*)d_in[5];
    const float* bqkv    = (const float*)d_in[6];
    const float* Wo      = (const float*)d_in[7];
    const float* bo      = (const float*)d_in[8];
    const float* W1      = (const float*)d_in[9];
    const float* b1      = (const float*)d_in[10];
    const float* W2      = (const float*)d_in[11];
    const float* b2      = (const float*)d_in[12];
    const float* g1      = (const float*)d_in[13];
    const float* be1     = (const float*)d_in[14];
    const float* g2      = (const float*)d_in[15];
    const float* be2     = (const float*)d_in[16];
    const float* Wm      = (const float*)d_in[17];
    const float* bm      = (const float*)d_in[18];
    const float* Wpi_m   = (const float*)d_in[19];
    const float* bpi_m   = (const float*)d_in[20];
    const float* Wmu_m   = (const float*)d_in[21];
    const float* bmu_m   = (const float*)d_in[22];
    const float* Wsg_m   = (const float*)d_in[23];
    const float* bsg_m   = (const float*)d_in[24];
    const float* Wpi_v   = (const float*)d_in[25];
    const float* bpi_v   = (const float*)d_in[26];
    const float* Wmu_v   = (const float*)d_in[27];
    const float* bmu_v   = (const float*)d_in[28];
    const float* Wsg_v   = (const float*)d_in[29];
    const float* bsg_v   = (const float*)d_in[30];
    float* out = (float*)d_out;

    char* ws = (char*)d_ws;                            // ~167 MB total
    float* pe      = (float*)(ws + 0);                 // 0.5 MB
    bf16*  xin     = (bf16*)(ws + 524288);             // 4.72 MB
    bf16*  wemb    = (bf16*)(ws + 5242880);            // 1.18 MB
    bf16*  whead   = (bf16*)(ws + 6422528);            // 1.31 MB (640 rows)
    float* bhead   = (float*)(ws + 7733248);           // 2.5 KB
    float* xf      = (float*)(ws + 7735808);           // 16.8 MB
    bf16*  xb      = (bf16*)(ws + 24513024);           // 8.4 MB
    bf16*  qkvb    = (bf16*)(ws + 32901632);           // 25.2 MB
    bf16*  ob      = (bf16*)(ws + 58067456);           // 8.4 MB (attn out, reused as FF hidden)
    float* tmp     = (float*)(ws + 66456064);          // 16.8 MB
    bf16*  wqb_all = (bf16*)(ws + 83233280);           // 37.7 MB (6 layers)
    bf16*  wob_all = (bf16*)(ws + 120982016);          // 12.6 MB
    bf16*  w1b_all = (bf16*)(ws + 133564928);          // 12.6 MB
    bf16*  w2b_all = (bf16*)(ws + 146147840);          // 12.6 MB
    float* hout    = (float*)(ws + 158730752);         // 8.6 MB

    prep_kernel<<<6272, 256, 0, stream>>>(input, targets, sos, W_emb,
                                          Wm, Wpi_m, Wmu_m, Wsg_m, Wpi_v, Wmu_v, Wsg_v,
                                          bm, bpi_m, bmu_m, bsg_m, bpi_v, bmu_v, bsg_v,
                                          pe, xin, wemb, whead, bhead);
    cvt_all_kernel<<<2048, 256, 0, stream>>>(Wqkv, Wo, W1, W2, wqb_all, wob_all, w1b_all, w2b_all);
    // x = XIN @ Wemb^T + b + pe   -> xf (f32) + xb (bf16)
    gemm_bt<4><<<dim3(8, 32, 1), 256, 0, stream>>>(xin, wemb, xf, xb, b_emb, nullptr, pe,
                                                   4096, 1024, 576, 576, 576, 1024, 0, 0);
    for (int l = 0; l < 6; ++l) {
        const bf16* wqb = wqb_all + (size_t)l * 3145728;
        const bf16* wob = wob_all + (size_t)l * 1048576;
        const bf16* w1b = w1b_all + (size_t)l * 1048576;
        const bf16* w2b = w2b_all + (size_t)l * 1048576;
        // qkv = x @ Wqkv^T + b  (bf16 out)
        gemm_bt<0><<<dim3(24, 32, 1), 256, 0, stream>>>(xb, wqb, nullptr, qkvb, bqkv + l * 3072,
                                                        nullptr, nullptr, 4096, 3072, 1024, 1024, 1024, 3072, 0, 0);
        attn_fused<<<512, 256, 0, stream>>>(qkvb, ob);
        // tmp = x + o @ Wo^T + bo
        gemm_bt<2><<<dim3(8, 32, 1), 256, 0, stream>>>(ob, wob, tmp, nullptr, bo + l * 1024,
                                                       xf, nullptr, 4096, 1024, 1024, 1024, 1024, 1024, 0, 0);
        ln_kernel<<<4096, 256, 0, stream>>>(tmp, g1 + l * 1024, be1 + l * 1024, xf, xb);
        // t1 = relu(x @ W1^T + b1) (bf16, reuse ob)
        gemm_bt<1><<<dim3(8, 32, 1), 256, 0, stream>>>(xb, w1b, nullptr, ob, b1 + l * 1024,
                                                       nullptr, nullptr, 4096, 1024, 1024, 1024, 1024, 1024, 0, 0);
        // tmp = x + t1 @ W2^T + b2
        gemm_bt<2><<<dim3(8, 32, 1), 256, 0, stream>>>(ob, w2b, tmp, nullptr, b2 + l * 1024,
                                                       xf, nullptr, 4096, 1024, 1024, 1024, 1024, 1024, 0, 0);
        ln_kernel<<<4096, 256, 0, stream>>>(tmp, g2 + l * 1024, be2 + l * 1024, xf, xb);
    }
    // heads: per-batch M=127 rows of x -> hout (B,127,529)
    gemm_bt<3><<<dim3(5, 1, 32), 256, 0, stream>>>(xb, whead, hout, nullptr, bhead, nullptr, nullptr,
                                                   127, 529, 1024, 1024, 1024, 529, 131072LL, 67183LL);
    finalize_kernel<<<4064, 256, 0, stream>>>(hout, out);
}

// Round 3
// 1227.508 us; speedup vs baseline: 1.0703x; 1.0703x over previous
//
#include <hip/hip_runtime.h>
#include <hip/hip_bf16.h>

typedef __hip_bfloat16 bf16;
typedef __attribute__((ext_vector_type(8))) short bfrag8;   // 8 bf16 (4 VGPR) MFMA A/B frag
typedef __attribute__((ext_vector_type(4))) float facc4;    // MFMA C/D frag
typedef __attribute__((ext_vector_type(4))) unsigned short us4;

#define AS1C const __attribute__((address_space(1))) void
#define AS3  __attribute__((address_space(3))) void

__device__ __forceinline__ void gload_lds16(const void* src, void* dst) {
    __builtin_amdgcn_global_load_lds((AS1C*)src, (AS3*)dst, 16, 0, 0);
}

__device__ __forceinline__ unsigned short f2bf(float f) {   // RNE, finite inputs
    unsigned u = __float_as_uint(f);
    unsigned r = u + 0x7FFFu + ((u >> 16) & 1u);
    return (unsigned short)(r >> 16);
}

// ---------------- merged prep kernel: pe | xin | wemb | whead ----------------
__global__ void prep_kernel(const float* __restrict__ input, const float* __restrict__ targets,
                            const float* __restrict__ sos, const float* __restrict__ W_emb,
                            const float* __restrict__ Wm, const float* __restrict__ Wpi_m,
                            const float* __restrict__ Wmu_m, const float* __restrict__ Wsg_m,
                            const float* __restrict__ Wpi_v, const float* __restrict__ Wmu_v,
                            const float* __restrict__ Wsg_v,
                            const float* __restrict__ bm, const float* __restrict__ bpi_m,
                            const float* __restrict__ bmu_m, const float* __restrict__ bsg_m,
                            const float* __restrict__ bpi_v, const float* __restrict__ bmu_v,
                            const float* __restrict__ bsg_v,
                            float* __restrict__ pe, bf16* __restrict__ xin,
                            bf16* __restrict__ wemb, bf16* __restrict__ whead,
                            float* __restrict__ bhead) {
    int bid = blockIdx.x;
    if (bid < 512) {                                     // pe [128][1024]
        int idx = bid * 256 + threadIdx.x;
        int s = idx >> 10, c = idx & 1023;
        int i = c >> 1;
        float div = expf(-9.210340371976184f * (float)(2 * i) * (1.f / 1024.f));
        float a = (float)s * div;
        pe[idx] = (c & 1) ? cosf(a) : sinf(a);
    } else if (bid < 512 + 4096) {                       // xin row (b*128+s), pad K->576
        int row = bid - 512;
        int b = row >> 7, s = row & 127;
        for (int c = threadIdx.x; c < 576; c += 256) {
            float v = 0.f;
            if (c < 512) v = input[b * 512 + c];
            else if (c < 545) {
                int j = c - 512;
                v = (s == 0) ? sos[j] : targets[((size_t)b * 127 + (s - 1)) * 33 + j];
            }
            xin[(size_t)row * 576 + c] = __float2bfloat16(v);
        }
    } else if (bid < 512 + 4096 + 1024) {                // wemb row, pad 545->576
        int row = bid - (512 + 4096);
        for (int c = threadIdx.x; c < 576; c += 256)
            wemb[(size_t)row * 576 + c] = __float2bfloat16(c < 545 ? W_emb[(size_t)row * 545 + c] : 0.f);
    } else {                                             // whead row (640 = 529 real + pad)
        int r = bid - (512 + 4096 + 1024);
        const float* wsrc = nullptr; const float* bsrc = nullptr; int off = 0;
        if (r == 0)        { wsrc = Wm;    bsrc = bm;    off = 0; }
        else if (r < 9)    { wsrc = Wpi_m; bsrc = bpi_m; off = r - 1; }
        else if (r < 137)  { wsrc = Wmu_m; bsrc = bmu_m; off = r - 9; }
        else if (r < 265)  { wsrc = Wsg_m; bsrc = bsg_m; off = r - 137; }
        else if (r < 273)  { wsrc = Wpi_v; bsrc = bpi_v; off = r - 265; }
        else if (r < 401)  { wsrc = Wmu_v; bsrc = bmu_v; off = r - 273; }
        else if (r < 529)  { wsrc = Wsg_v; bsrc = bsg_v; off = r - 401; }
        for (int c = threadIdx.x; c < 1024; c += 256)
            whead[(size_t)r * 1024 + c] = __float2bfloat16(wsrc ? wsrc[(size_t)off * 1024 + c] : 0.f);
        if (threadIdx.x == 0 && wsrc) bhead[r] = bsrc[off];
    }
}

// ---------------- one-shot weight conversion for ALL layers ----------------
// per-layer float4 counts: Wqkv 786432 | Wo 262144 | W1 262144 | W2 262144 = 1572864
// vectorized us4 stores (scalar bf16 stores were the round-2 2.4 TB/s bottleneck)
__global__ void cvt_all_kernel(const float* __restrict__ Wqkv, const float* __restrict__ Wo,
                               const float* __restrict__ W1, const float* __restrict__ W2,
                               bf16* __restrict__ wqb, bf16* __restrict__ wob,
                               bf16* __restrict__ w1b, bf16* __restrict__ w2b) {
    const int NTOT = 9437184;                            // 6 layers * 1572864
    for (int i = blockIdx.x * 256 + threadIdx.x; i < NTOT; i += gridDim.x * 256) {
        int l = i / 1572864;
        int r = i - l * 1572864;
        const float* src; bf16* dst; size_t o;
        if (r < 786432)       { src = Wqkv + (size_t)l * 3145728; dst = wqb + (size_t)l * 3145728; o = (size_t)r * 4; }
        else if (r < 1048576) { src = Wo   + (size_t)l * 1048576; dst = wob + (size_t)l * 1048576; o = (size_t)(r - 786432) * 4; }
        else if (r < 1310720) { src = W1   + (size_t)l * 1048576; dst = w1b + (size_t)l * 1048576; o = (size_t)(r - 1048576) * 4; }
        else                  { src = W2   + (size_t)l * 1048576; dst = w2b + (size_t)l * 1048576; o = (size_t)(r - 1310720) * 4; }
        float4 v = *(const float4*)(src + o);
        us4 s;
        s.x = f2bf(v.x); s.y = f2bf(v.y); s.z = f2bf(v.z); s.w = f2bf(v.w);
        *(us4*)(dst + o) = s;
    }
}

// ---------------- main GEMM: C[M,N] = A[M,K] @ B[N,K]^T (+epilogue) ----------------
// 128x128 tile, BK=64, 4 waves (each 64x64 of 16x16x32 bf16 MFMA).
// DBUF=1: double-buffered LDS prefetch (for grid-limited <=256-block launches,
//         1 block/CU -> prefetch is the only latency hiding). 64KB LDS, 2 blocks/CU.
// DBUF=0: single-buffer 32KB, __launch_bounds__(256,3) -> 3 blocks/CU; cross-block
//         wave overlap hides staging (m97/m114 regime). Used for QKV (768 blocks).
// LDS XOR-swizzle (byte ^ ((row&7)<<4)) via pre-swizzled global source (linear LDS dest).
// EPI: 0 bias->bf16 | 1 bias+relu->bf16 | 2 bias+res->f32 | 3 bias->f32 | 4 bias+pe->f32+bf16
template<int EPI, int DBUF>
__global__ __launch_bounds__(256, DBUF ? 2 : 3) void gemm_bt(
    const bf16* __restrict__ A, const bf16* __restrict__ Bw,
    float* __restrict__ Cf, bf16* __restrict__ Cb,
    const float* __restrict__ bias, const float* __restrict__ res, const float* __restrict__ pe,
    int M, int N, int K, int lda, int ldb, int ldc, long long Az, long long Cz)
{
    __shared__ __align__(16) bf16 sA[DBUF ? 2 : 1][128 * 64];
    __shared__ __align__(16) bf16 sB[DBUF ? 2 : 1][128 * 64];
    const int t = threadIdx.x;
    const int w = t >> 6, la = t & 63;
    const int wm = (w >> 1) * 64, wn = (w & 1) * 64;
    const int m0 = blockIdx.y * 128, n0 = blockIdx.x * 128;
    const int z = blockIdx.z;
    A += (long long)z * Az;

    const int c0 = w * 64 + la;
    facc4 zero4 = {0.f, 0.f, 0.f, 0.f};
    facc4 acc[4][4];
#pragma unroll
    for (int mi = 0; mi < 4; ++mi)
#pragma unroll
        for (int ni = 0; ni < 4; ++ni) acc[mi][ni] = zero4;

    auto stage = [&](int buf, int kt) {
#pragma unroll
        for (int i = 0; i < 4; ++i) {
            int c = i * 256 + c0;
            int r = c >> 3;
            int bc = ((c & 7) * 16) ^ ((r & 7) << 4);   // pre-swizzled source byte col
            gload_lds16(A + (size_t)(m0 + r) * lda + kt + (bc >> 1),
                        (char*)sA[buf] + (size_t)(i * 256 + c0) * 16);
            gload_lds16(Bw + (size_t)(n0 + r) * ldb + kt + (bc >> 1),
                        (char*)sB[buf] + (size_t)(i * 256 + c0) * 16);
        }
    };
    auto compute = [&](int buf) {
#pragma unroll
        for (int ks = 0; ks < 2; ++ks) {
            bfrag8 af[4], bfv[4];
            const int koffb = (ks * 32 + (la >> 4) * 8) * 2;
#pragma unroll
            for (int i = 0; i < 4; ++i) {
                int rowa = wm + i * 16 + (la & 15);
                af[i] = *(const bfrag8*)((const char*)sA[buf] + rowa * 128 + (koffb ^ ((rowa & 7) << 4)));
                int rowb = wn + i * 16 + (la & 15);
                bfv[i] = *(const bfrag8*)((const char*)sB[buf] + rowb * 128 + (koffb ^ ((rowb & 7) << 4)));
            }
#pragma unroll
            for (int mi = 0; mi < 4; ++mi)
#pragma unroll
                for (int ni = 0; ni < 4; ++ni)
                    acc[mi][ni] = __builtin_amdgcn_mfma_f32_16x16x32_bf16(af[mi], bfv[ni], acc[mi][ni], 0, 0, 0);
        }
    };

    const int nk = K >> 6;
    if constexpr (DBUF) {
        stage(0, 0);
        __syncthreads();
        int cur = 0;
        for (int kt = 0; kt < nk; ++kt) {
            if (kt + 1 < nk) stage(cur ^ 1, (kt + 1) << 6);
            compute(cur);
            __syncthreads();        // drains stage(k+1) vmcnt; frees cur
            cur ^= 1;
        }
    } else {
        for (int kt = 0; kt < nk; ++kt) {
            stage(0, kt << 6);
            __syncthreads();
            compute(0);
            __syncthreads();
        }
    }
    // epilogue
#pragma unroll
    for (int mi = 0; mi < 4; ++mi) {
#pragma unroll
        for (int ni = 0; ni < 4; ++ni) {
            int col = n0 + wn + ni * 16 + (la & 15);
            if (col >= N) continue;
            float bv = bias[col];
#pragma unroll
            for (int j = 0; j < 4; ++j) {
                int row = m0 + wm + mi * 16 + (la >> 4) * 4 + j;
                if (row >= M) continue;
                float v = acc[mi][ni][j] + bv;
                size_t cidx = (size_t)z * Cz + (size_t)row * ldc + col;
                if constexpr (EPI == 0) {
                    Cb[cidx] = __float2bfloat16(v);
                } else if constexpr (EPI == 1) {
                    Cb[cidx] = __float2bfloat16(v > 0.f ? v : 0.f);
                } else if constexpr (EPI == 2) {
                    Cf[cidx] = v + res[(size_t)row * ldc + col];
                } else if constexpr (EPI == 3) {
                    Cf[cidx] = v;
                } else {
                    float u = v + pe[(size_t)(row & 127) * 1024 + col];
                    Cf[cidx] = u;
                    Cb[cidx] = __float2bfloat16(u);
                }
            }
        }
    }
}

// ---------------- fused attention: one block per (b,h) ----------------
// S=128, D=64. QK^T -> causal softmax (fp32 math, bf16 storage) -> PV. 64KB LDS.
__global__ __launch_bounds__(256) void attn_fused(const bf16* __restrict__ qkv, bf16* __restrict__ obf)
{
    __shared__ __align__(16) char lds[65536];
    char* sQ  = lds;            // [128] rows x 128B, swizzled
    char* sK  = lds + 16384;    // [128] rows x 128B
    char* sS  = lds + 32768;    // [128] rows x 256B bf16 (scores, then P)
    char* sVT = lds;            // [64] rows x 256B (V transposed), overlaps sQ

    const int t = threadIdx.x, w = t >> 6, la = t & 63;
    const int b = blockIdx.x >> 4, h = blockIdx.x & 15;
    const size_t base = (size_t)b * 128 * 3072 + (size_t)h * 64;

    // phase 1: stage Q, K (swizzled via pre-swizzled source)
#pragma unroll
    for (int i = 0; i < 4; ++i) {
        int c = i * 256 + w * 64 + la;
        int r = c >> 3;
        int bc = ((c & 7) * 16) ^ ((r & 7) << 4);
        gload_lds16(qkv + base + (size_t)r * 3072 + (bc >> 1),
                    sQ + (size_t)(i * 256 + w * 64) * 16);
        gload_lds16(qkv + base + 1024 + (size_t)r * 3072 + (bc >> 1),
                    sK + (size_t)(i * 256 + w * 64) * 16);
    }
    __syncthreads();

    // phase 2: S = Q K^T * 0.125
    const int wm = (w >> 1) * 64, wn = (w & 1) * 64;
    facc4 zero4 = {0.f, 0.f, 0.f, 0.f};
    {
        facc4 acc[4][4];
#pragma unroll
        for (int mi = 0; mi < 4; ++mi)
#pragma unroll
            for (int ni = 0; ni < 4; ++ni) acc[mi][ni] = zero4;
#pragma unroll
        for (int ks = 0; ks < 2; ++ks) {
            bfrag8 af[4], bfv[4];
            const int koffb = (ks * 32 + (la >> 4) * 8) * 2;
#pragma unroll
            for (int i = 0; i < 4; ++i) {
                int rowa = wm + i * 16 + (la & 15);
                af[i] = *(const bfrag8*)(sQ + rowa * 128 + (koffb ^ ((rowa & 7) << 4)));
                int rowb = wn + i * 16 + (la & 15);
                bfv[i] = *(const bfrag8*)(sK + rowb * 128 + (koffb ^ ((rowb & 7) << 4)));
            }
#pragma unroll
            for (int mi = 0; mi < 4; ++mi)
#pragma unroll
                for (int ni = 0; ni < 4; ++ni)
                    acc[mi][ni] = __builtin_amdgcn_mfma_f32_16x16x32_bf16(af[mi], bfv[ni], acc[mi][ni], 0, 0, 0);
        }
#pragma unroll
        for (int mi = 0; mi < 4; ++mi)
#pragma unroll
            for (int ni = 0; ni < 4; ++ni)
#pragma unroll
                for (int j = 0; j < 4; ++j) {
                    int row = wm + mi * 16 + (la >> 4) * 4 + j;
                    int col = wn + ni * 16 + (la & 15);
                    *(bf16*)(sS + row * 256 + ((2 * col) ^ ((row & 7) << 4))) =
                        __float2bfloat16(acc[mi][ni][j] * 0.125f);
                }
    }
    __syncthreads();

    // phase 3a: stage V transposed into sVT (sQ space, free now)
#pragma unroll
    for (int i = 0; i < 4; ++i) {
        int c = i * 256 + t;
        int r = c >> 3;             // key index s'
        int d0 = (c & 7) * 8;
        bfrag8 vv = *(const bfrag8*)(qkv + base + 2048 + (size_t)r * 3072 + d0);
#pragma unroll
        for (int j = 0; j < 8; ++j) {
            int d = d0 + j;
            *(short*)(sVT + d * 256 + ((2 * r) ^ ((d & 7) << 4))) = vv[j];
        }
    }
    // phase 3b: causal softmax, in place on sS (wave w owns rows w*32..w*32+31)
    for (int ri = 0; ri < 32; ++ri) {
        int r = w * 32 + ri;
        int c1 = la, c2 = la + 64;
        float v1 = (c1 <= r) ? __bfloat162float(*(const bf16*)(sS + r * 256 + ((2 * c1) ^ ((r & 7) << 4)))) : -1e30f;
        float v2 = (c2 <= r) ? __bfloat162float(*(const bf16*)(sS + r * 256 + ((2 * c2) ^ ((r & 7) << 4)))) : -1e30f;
        float mx = fmaxf(v1, v2);
#pragma unroll
        for (int off = 32; off; off >>= 1) mx = fmaxf(mx, __shfl_xor(mx, off));
        float e1 = (c1 <= r) ? __expf(v1 - mx) : 0.f;
        float e2 = (c2 <= r) ? __expf(v2 - mx) : 0.f;
        float sm = e1 + e2;
#pragma unroll
        for (int off = 32; off; off >>= 1) sm += __shfl_xor(sm, off);
        float inv = 1.f / sm;
        *(bf16*)(sS + r * 256 + ((2 * c1) ^ ((r & 7) << 4))) = __float2bfloat16(e1 * inv);
        *(bf16*)(sS + r * 256 + ((2 * c2) ^ ((r & 7) << 4))) = __float2bfloat16(e2 * inv);
    }
    __syncthreads();

    // phase 4: O = P V  (wave tile 64M x 32N, K=128)
    const int wm2 = (w >> 1) * 64, wn2 = (w & 1) * 32;
    facc4 a2[4][2];
#pragma unroll
    for (int mi = 0; mi < 4; ++mi) { a2[mi][0] = zero4; a2[mi][1] = zero4; }
#pragma unroll
    for (int ks = 0; ks < 4; ++ks) {
        bfrag8 pa[4], vb[2];
        const int koffb = (ks * 32 + (la >> 4) * 8) * 2;
#pragma unroll
        for (int mi = 0; mi < 4; ++mi) {
            int rowa = wm2 + mi * 16 + (la & 15);
            pa[mi] = *(const bfrag8*)(sS + rowa * 256 + (koffb ^ ((rowa & 7) << 4)));
        }
#pragma unroll
        for (int ni = 0; ni < 2; ++ni) {
            int rowb = wn2 + ni * 16 + (la & 15);
            vb[ni] = *(const bfrag8*)(sVT + rowb * 256 + (koffb ^ ((rowb & 7) << 4)));
        }
#pragma unroll
        for (int mi = 0; mi < 4; ++mi)
#pragma unroll
            for (int ni = 0; ni < 2; ++ni)
                a2[mi][ni] = __builtin_amdgcn_mfma_f32_16x16x32_bf16(pa[mi], vb[ni], a2[mi][ni], 0, 0, 0);
    }
#pragma unroll
    for (int mi = 0; mi < 4; ++mi)
#pragma unroll
        for (int ni = 0; ni < 2; ++ni)
#pragma unroll
            for (int j = 0; j < 4; ++j) {
                int s = wm2 + mi * 16 + (la >> 4) * 4 + j;
                int d = wn2 + ni * 16 + (la & 15);
                obf[((size_t)(b * 128 + s)) * 1024 + h * 64 + d] = __float2bfloat16(a2[mi][ni][j]);
            }
}

// ---------------- LayerNorm (one block per row of 1024) ----------------
__global__ __launch_bounds__(256) void ln_kernel(const float* __restrict__ in, const float* __restrict__ g,
                                                 const float* __restrict__ be,
                                                 float* __restrict__ outf, bf16* __restrict__ outb)
{
    const int row = blockIdx.x, t = threadIdx.x;
    const float* x = in + (size_t)row * 1024;
    float4 v = *(const float4*)(x + t * 4);
    float s = v.x + v.y + v.z + v.w;
    float q = v.x * v.x + v.y * v.y + v.z * v.z + v.w * v.w;
#pragma unroll
    for (int off = 32; off; off >>= 1) {
        s += __shfl_xor(s, off);
        q += __shfl_xor(q, off);
    }
    __shared__ float ssum[4], sqs[4];
    if ((t & 63) == 0) { ssum[t >> 6] = s; sqs[t >> 6] = q; }
    __syncthreads();
    s = ssum[0] + ssum[1] + ssum[2] + ssum[3];
    q = sqs[0] + sqs[1] + sqs[2] + sqs[3];
    float mean = s * (1.f / 1024.f);
    float var = q * (1.f / 1024.f) - mean * mean;
    float rstd = rsqrtf(var + 1e-5f);
    float4 gv = *(const float4*)(g + t * 4);
    float4 bv = *(const float4*)(be + t * 4);
    size_t o = (size_t)row * 1024 + t * 4;
    float o0 = (v.x - mean) * rstd * gv.x + bv.x;
    float o1 = (v.y - mean) * rstd * gv.y + bv.y;
    float o2 = (v.z - mean) * rstd * gv.z + bv.z;
    float o3 = (v.w - mean) * rstd * gv.w + bv.w;
    outf[o + 0] = o0; outf[o + 1] = o1; outf[o + 2] = o2; outf[o + 3] = o3;
    outb[o + 0] = __float2bfloat16(o0); outb[o + 1] = __float2bfloat16(o1);
    outb[o + 2] = __float2bfloat16(o2); outb[o + 3] = __float2bfloat16(o3);
}

// ---------------- MDN finalize / scatter ----------------
__global__ void finalize_kernel(const float* __restrict__ hout, float* __restrict__ out) {
    const size_t O_PI_M = 0, O_MU_M = 32512, O_VAR_M = 552704, O_PI_V = 1072896,
                 O_MU_V = 1105408, O_VAR_V = 1625600, O_MASK = 2145792;
    int rm = blockIdx.x;                    // b*127+m, 4064 rows
    const float* hrow = hout + (size_t)rm * 529;
    int t = threadIdx.x;
    if (t < 128) {
        out[O_MU_M  + (size_t)rm * 128 + t] = hrow[9 + t];
        out[O_VAR_M + (size_t)rm * 128 + t] = expf(hrow[137 + t]);
        out[O_MU_V  + (size_t)rm * 128 + t] = hrow[273 + t];
        out[O_VAR_V + (size_t)rm * 128 + t] = expf(hrow[401 + t]);
    } else if (t == 128) {
        out[O_MASK + rm] = hrow[0];
    } else if (t == 129 || t == 130) {
        int boff = (t == 129) ? 1 : 265;
        size_t oo = ((t == 129) ? O_PI_M : O_PI_V) + (size_t)rm * 8;
        float v[8], mx = -1e30f;
#pragma unroll
        for (int j = 0; j < 8; ++j) { v[j] = hrow[boff + j]; mx = fmaxf(mx, v[j]); }
        float sm = 0.f;
#pragma unroll
        for (int j = 0; j < 8; ++j) { v[j] = expf(v[j] - mx); sm += v[j]; }
        float inv = 1.f / sm;
#pragma unroll
        for (int j = 0; j < 8; ++j) out[oo + j] = v[j] * inv;
    }
}

// ---------------- launcher ----------------
extern "C" void kernel_launch(void* const* d_in, const int* in_sizes, int n_in,
                              void* d_out, int out_size, void* d_ws, size_t ws_size,
                              hipStream_t stream) {
    (void)in_sizes; (void)n_in; (void)out_size; (void)ws_size;
    const float* input   = (const float*)d_in[0];
    const float* targets = (const float*)d_in[1];
    const float* W_emb   = (const float*)d_in[2];
    const float* b_emb   = (const float*)d_in[3];
    const float* sos     = (const float*)d_in[4];
    const float* Wqkv    = (const float*)d_in[5];
    const float* bqkv    = (const float*)d_in[6];
    const float* Wo      = (const float*)d_in[7];
    const float* bo      = (const float*)d_in[8];
    const float* W1      = (const float*)d_in[9];
    const float* b1      = (const float*)d_in[10];
    const float* W2      = (const float*)d_in[11];
    const float* b2      = (const float*)d_in[12];
    const float* g1      = (const float*)d_in[13];
    const float* be1     = (const float*)d_in[14];
    const float* g2      = (const float*)d_in[15];
    const float* be2     = (const float*)d_in[16];
    const float* Wm      = (const float*)d_in[17];
    const float* bm      = (const float*)d_in[18];
    const float* Wpi_m   = (const float*)d_in[19];
    const float* bpi_m   = (const float*)d_in[20];
    const float* Wmu_m   = (const float*)d_in[21];
    const float* bmu_m   = (const float*)d_in[22];
    const float* Wsg_m   = (const float*)d_in[23];
    const float* bsg_m   = (const float*)d_in[24];
    const float* Wpi_v   = (const float*)d_in[25];
    const float* bpi_v   = (const float*)d_in[26];
    const float* Wmu_v   = (const float*)d_in[27];
    const float* bmu_v   = (const float*)d_in[28];
    const float* Wsg_v   = (const float*)d_in[29];
    const float* bsg_v   = (const float*)d_in[30];
    float* out = (float*)d_out;

    char* ws = (char*)d_ws;                            // ~167 MB total
    float* pe      = (float*)(ws + 0);                 // 0.5 MB
    bf16*  xin     = (bf16*)(ws + 524288);             // 4.72 MB
    bf16*  wemb    = (bf16*)(ws + 5242880);            // 1.18 MB
    bf16*  whead   = (bf16*)(ws + 6422528);            // 1.31 MB (640 rows)
    float* bhead   = (float*)(ws + 7733248);           // 2.5 KB
    float* xf      = (float*)(ws + 7735808);           // 16.8 MB
    bf16*  xb      = (bf16*)(ws + 24513024);           // 8.4 MB
    bf16*  qkvb    = (bf16*)(ws + 32901632);           // 25.2 MB
    bf16*  ob      = (bf16*)(ws + 58067456);           // 8.4 MB (attn out, reused as FF hidden)
    float* tmp     = (float*)(ws + 66456064);          // 16.8 MB
    bf16*  wqb_all = (bf16*)(ws + 83233280);           // 37.7 MB (6 layers)
    bf16*  wob_all = (bf16*)(ws + 120982016);          // 12.6 MB
    bf16*  w1b_all = (bf16*)(ws + 133564928);          // 12.6 MB
    bf16*  w2b_all = (bf16*)(ws + 146147840);          // 12.6 MB
    float* hout    = (float*)(ws + 158730752);         // 8.6 MB

    prep_kernel<<<6272, 256, 0, stream>>>(input, targets, sos, W_emb,
                                          Wm, Wpi_m, Wmu_m, Wsg_m, Wpi_v, Wmu_v, Wsg_v,
                                          bm, bpi_m, bmu_m, bsg_m, bpi_v, bmu_v, bsg_v,
                                          pe, xin, wemb, whead, bhead);
    cvt_all_kernel<<<2048, 256, 0, stream>>>(Wqkv, Wo, W1, W2, wqb_all, wob_all, w1b_all, w2b_all);
    // x = XIN @ Wemb^T + b + pe   -> xf (f32) + xb (bf16)
    gemm_bt<4, 1><<<dim3(8, 32, 1), 256, 0, stream>>>(xin, wemb, xf, xb, b_emb, nullptr, pe,
                                                      4096, 1024, 576, 576, 576, 1024, 0, 0);
    for (int l = 0; l < 6; ++l) {
        const bf16* wqb = wqb_all + (size_t)l * 3145728;
        const bf16* wob = wob_all + (size_t)l * 1048576;
        const bf16* w1b = w1b_all + (size_t)l * 1048576;
        const bf16* w2b = w2b_all + (size_t)l * 1048576;
        // qkv = x @ Wqkv^T + b  (bf16 out) -- 768 blocks, single-buffer, 3 blocks/CU
        gemm_bt<0, 0><<<dim3(24, 32, 1), 256, 0, stream>>>(xb, wqb, nullptr, qkvb, bqkv + l * 3072,
                                                           nullptr, nullptr, 4096, 3072, 1024, 1024, 1024, 3072, 0, 0);
        attn_fused<<<512, 256, 0, stream>>>(qkvb, ob);
        // tmp = x + o @ Wo^T + bo -- 256 blocks, dbuf prefetch
        gemm_bt<2, 1><<<dim3(8, 32, 1), 256, 0, stream>>>(ob, wob, tmp, nullptr, bo + l * 1024,
                                                          xf, nullptr, 4096, 1024, 1024, 1024, 1024, 1024, 0, 0);
        ln_kernel<<<4096, 256, 0, stream>>>(tmp, g1 + l * 1024, be1 + l * 1024, xf, xb);
        // t1 = relu(x @ W1^T + b1) (bf16, reuse ob)
        gemm_bt<1, 1><<<dim3(8, 32, 1), 256, 0, stream>>>(xb, w1b, nullptr, ob, b1 + l * 1024,
                                                          nullptr, nullptr, 4096, 1024, 1024, 1024, 1024, 1024, 0, 0);
        // tmp = x + t1 @ W2^T + b2
        gemm_bt<2, 1><<<dim3(8, 32, 1), 256, 0, stream>>>(ob, w2b, tmp, nullptr, b2 + l * 1024,
                                                          xf, nullptr, 4096, 1024, 1024, 1024, 1024, 1024, 0, 0);
        ln_kernel<<<4096, 256, 0, stream>>>(tmp, g2 + l * 1024, be2 + l * 1024, xf, xb);
    }
    // heads: per-batch M=127 rows of x -> hout (B,127,529) -- 160 blocks, dbuf
    gemm_bt<3, 1><<<dim3(5, 1, 32), 256, 0, stream>>>(xb, whead, hout, nullptr, bhead, nullptr, nullptr,
                                                      127, 529, 1024, 1024, 1024, 529, 131072LL, 67183LL);
    finalize_kernel<<<4064, 256, 0, stream>>>(hout, out);
}

// Round 4
// 967.133 us; speedup vs baseline: 1.3584x; 1.2692x over previous
//
#include <hip/hip_runtime.h>
#include <hip/hip_bf16.h>

typedef __hip_bfloat16 bf16;
typedef __attribute__((ext_vector_type(8))) short bfrag8;   // 8 bf16 (4 VGPR) MFMA A/B frag
typedef __attribute__((ext_vector_type(4))) float facc4;    // MFMA C/D frag
typedef __attribute__((ext_vector_type(4))) unsigned short us4;

#define AS1C const __attribute__((address_space(1))) void
#define AS3  __attribute__((address_space(3))) void

__device__ __forceinline__ void gload_lds16(const void* src, void* dst) {
    __builtin_amdgcn_global_load_lds((AS1C*)src, (AS3*)dst, 16, 0, 0);
}

__device__ __forceinline__ unsigned short f2bf(float f) {   // RNE, finite inputs
    unsigned u = __float_as_uint(f);
    unsigned r = u + 0x7FFFu + ((u >> 16) & 1u);
    return (unsigned short)(r >> 16);
}

// ---------------- merged prep kernel: pe | xin | wemb | whead ----------------
__global__ void prep_kernel(const float* __restrict__ input, const float* __restrict__ targets,
                            const float* __restrict__ sos, const float* __restrict__ W_emb,
                            const float* __restrict__ Wm, const float* __restrict__ Wpi_m,
                            const float* __restrict__ Wmu_m, const float* __restrict__ Wsg_m,
                            const float* __restrict__ Wpi_v, const float* __restrict__ Wmu_v,
                            const float* __restrict__ Wsg_v,
                            const float* __restrict__ bm, const float* __restrict__ bpi_m,
                            const float* __restrict__ bmu_m, const float* __restrict__ bsg_m,
                            const float* __restrict__ bpi_v, const float* __restrict__ bmu_v,
                            const float* __restrict__ bsg_v,
                            float* __restrict__ pe, bf16* __restrict__ xin,
                            bf16* __restrict__ wemb, bf16* __restrict__ whead,
                            float* __restrict__ bhead) {
    int bid = blockIdx.x;
    if (bid < 512) {                                     // pe [128][1024]
        int idx = bid * 256 + threadIdx.x;
        int s = idx >> 10, c = idx & 1023;
        int i = c >> 1;
        float div = expf(-9.210340371976184f * (float)(2 * i) * (1.f / 1024.f));
        float a = (float)s * div;
        pe[idx] = (c & 1) ? cosf(a) : sinf(a);
    } else if (bid < 512 + 4096) {                       // xin row (b*128+s), pad K->576
        int row = bid - 512;
        int b = row >> 7, s = row & 127;
        for (int c = threadIdx.x; c < 576; c += 256) {
            float v = 0.f;
            if (c < 512) v = input[b * 512 + c];
            else if (c < 545) {
                int j = c - 512;
                v = (s == 0) ? sos[j] : targets[((size_t)b * 127 + (s - 1)) * 33 + j];
            }
            xin[(size_t)row * 576 + c] = __float2bfloat16(v);
        }
    } else if (bid < 512 + 4096 + 1024) {                // wemb row, pad 545->576
        int row = bid - (512 + 4096);
        for (int c = threadIdx.x; c < 576; c += 256)
            wemb[(size_t)row * 576 + c] = __float2bfloat16(c < 545 ? W_emb[(size_t)row * 545 + c] : 0.f);
    } else {                                             // whead row (640 = 529 real + pad)
        int r = bid - (512 + 4096 + 1024);
        const float* wsrc = nullptr; const float* bsrc = nullptr; int off = 0;
        if (r == 0)        { wsrc = Wm;    bsrc = bm;    off = 0; }
        else if (r < 9)    { wsrc = Wpi_m; bsrc = bpi_m; off = r - 1; }
        else if (r < 137)  { wsrc = Wmu_m; bsrc = bmu_m; off = r - 9; }
        else if (r < 265)  { wsrc = Wsg_m; bsrc = bsg_m; off = r - 137; }
        else if (r < 273)  { wsrc = Wpi_v; bsrc = bpi_v; off = r - 265; }
        else if (r < 401)  { wsrc = Wmu_v; bsrc = bmu_v; off = r - 273; }
        else if (r < 529)  { wsrc = Wsg_v; bsrc = bsg_v; off = r - 401; }
        for (int c = threadIdx.x; c < 1024; c += 256)
            whead[(size_t)r * 1024 + c] = __float2bfloat16(wsrc ? wsrc[(size_t)off * 1024 + c] : 0.f);
        if (threadIdx.x == 0 && wsrc) bhead[r] = bsrc[off];
    }
}

// ---------------- one-shot weight conversion for ALL layers ----------------
// Block-partitioned segments (no per-iteration div/branch). 192 blocks/layer:
// [0,96) Wqkv | [96,128) Wo | [128,160) W1 | [160,192) W2 ; 8192 float4 per block.
__global__ void cvt_all_kernel(const float* __restrict__ Wqkv, const float* __restrict__ Wo,
                               const float* __restrict__ W1, const float* __restrict__ W2,
                               bf16* __restrict__ wqb, bf16* __restrict__ wob,
                               bf16* __restrict__ w1b, bf16* __restrict__ w2b) {
    int bid = blockIdx.x;                 // 1152 = 6 layers * 192
    int l = bid / 192;
    int s = bid - l * 192;
    const float* src; bf16* dst;
    if (s < 96)       { src = Wqkv + (size_t)l * 3145728; dst = wqb + (size_t)l * 3145728; }
    else if (s < 128) { src = Wo + (size_t)l * 1048576; dst = wob + (size_t)l * 1048576; s -= 96; }
    else if (s < 160) { src = W1 + (size_t)l * 1048576; dst = w1b + (size_t)l * 1048576; s -= 128; }
    else              { src = W2 + (size_t)l * 1048576; dst = w2b + (size_t)l * 1048576; s -= 160; }
    size_t base = ((size_t)s * 8192 + threadIdx.x) * 4;
#pragma unroll 4
    for (int it = 0; it < 32; ++it) {
        size_t o = base + (size_t)it * 1024;         // 256 threads * 4 floats
        float4 v = *(const float4*)(src + o);
        us4 w2;
        w2.x = f2bf(v.x); w2.y = f2bf(v.y); w2.z = f2bf(v.z); w2.w = f2bf(v.w);
        *(us4*)(dst + o) = w2;
    }
}

// ---------------- main GEMM: C[M,N] = A[M,K] @ B[N,K]^T (+epilogue) ----------------
// 128x128 tile, BK=64, 4 waves (each 64x64 of 16x16x32 bf16 MFMA).
// OPERAND-SWAPPED MFMA: acc = mfma(B_frag, A_frag) computes C^T fragments, so each
// thread holds row = lane&15 (fixed) and 4 CONSECUTIVE cols (lane>>4)*4+j -> all
// epilogue stores vectorize (us4 8B bf16 / float4 16B fp32) and bias/res/pe load float4.
// DBUF=1: double-buffered prefetch for grid-limited (<=256-block) launches.
// DBUF=0: single-buffer, 3 blocks/CU (cross-block overlap regime) for QKV.
// EPI: 0 bias->bf16 | 1 bias+relu->bf16 | 2 bias+res->f32 | 3 bias->f32 scalar (odd ldc) | 4 bias+pe->f32+bf16
template<int EPI, int DBUF>
__global__ __launch_bounds__(256, DBUF ? 2 : 3) void gemm_bt(
    const bf16* __restrict__ A, const bf16* __restrict__ Bw,
    float* __restrict__ Cf, bf16* __restrict__ Cb,
    const float* __restrict__ bias, const float* __restrict__ res, const float* __restrict__ pe,
    int M, int N, int K, int lda, int ldb, int ldc, long long Az, long long Cz)
{
    __shared__ __align__(16) bf16 sA[DBUF ? 2 : 1][128 * 64];
    __shared__ __align__(16) bf16 sB[DBUF ? 2 : 1][128 * 64];
    const int t = threadIdx.x;
    const int w = t >> 6, la = t & 63;
    const int wm = (w >> 1) * 64, wn = (w & 1) * 64;
    const int m0 = blockIdx.y * 128, n0 = blockIdx.x * 128;
    const int z = blockIdx.z;
    A += (long long)z * Az;

    const int c0 = w * 64 + la;
    facc4 zero4 = {0.f, 0.f, 0.f, 0.f};
    facc4 acc[4][4];
#pragma unroll
    for (int mi = 0; mi < 4; ++mi)
#pragma unroll
        for (int ni = 0; ni < 4; ++ni) acc[mi][ni] = zero4;

    auto stage = [&](int buf, int kt) {
#pragma unroll
        for (int i = 0; i < 4; ++i) {
            int c = i * 256 + c0;
            int r = c >> 3;
            int bc = ((c & 7) * 16) ^ ((r & 7) << 4);   // pre-swizzled source byte col
            gload_lds16(A + (size_t)(m0 + r) * lda + kt + (bc >> 1),
                        (char*)sA[buf] + (size_t)(i * 256 + c0) * 16);
            gload_lds16(Bw + (size_t)(n0 + r) * ldb + kt + (bc >> 1),
                        (char*)sB[buf] + (size_t)(i * 256 + c0) * 16);
        }
    };
    auto compute = [&](int buf) {
#pragma unroll
        for (int ks = 0; ks < 2; ++ks) {
            bfrag8 af[4], bfv[4];
            const int koffb = (ks * 32 + (la >> 4) * 8) * 2;
#pragma unroll
            for (int i = 0; i < 4; ++i) {
                int rowa = wm + i * 16 + (la & 15);
                af[i] = *(const bfrag8*)((const char*)sA[buf] + rowa * 128 + (koffb ^ ((rowa & 7) << 4)));
                int rowb = wn + i * 16 + (la & 15);
                bfv[i] = *(const bfrag8*)((const char*)sB[buf] + rowb * 128 + (koffb ^ ((rowb & 7) << 4)));
            }
#pragma unroll
            for (int mi = 0; mi < 4; ++mi)
#pragma unroll
                for (int ni = 0; ni < 4; ++ni)     // swapped operands -> C^T fragment
                    acc[mi][ni] = __builtin_amdgcn_mfma_f32_16x16x32_bf16(bfv[ni], af[mi], acc[mi][ni], 0, 0, 0);
        }
    };

    const int nk = K >> 6;
    if constexpr (DBUF) {
        stage(0, 0);
        __syncthreads();
        int cur = 0;
        for (int kt = 0; kt < nk; ++kt) {
            if (kt + 1 < nk) stage(cur ^ 1, (kt + 1) << 6);
            compute(cur);
            __syncthreads();        // drains stage(k+1) vmcnt; frees cur
            cur ^= 1;
        }
    } else {
        for (int kt = 0; kt < nk; ++kt) {
            stage(0, kt << 6);
            __syncthreads();
            compute(0);
            __syncthreads();
        }
    }
    // epilogue: thread holds C[row][colb..colb+3]
#pragma unroll
    for (int mi = 0; mi < 4; ++mi) {
        int row = m0 + wm + mi * 16 + (la & 15);
#pragma unroll
        for (int ni = 0; ni < 4; ++ni) {
            int colb = n0 + wn + ni * 16 + (la >> 4) * 4;
            if constexpr (EPI == 3) {               // scalar path (odd ldc / edge guards)
                if (row >= M) continue;
#pragma unroll
                for (int j = 0; j < 4; ++j) {
                    int col = colb + j;
                    if (col < N)
                        Cf[(size_t)z * Cz + (size_t)row * ldc + col] = acc[mi][ni][j] + bias[col];
                }
            } else {
                float4 bv = *(const float4*)(bias + colb);
                facc4 v = acc[mi][ni];
                v[0] += bv.x; v[1] += bv.y; v[2] += bv.z; v[3] += bv.w;
                size_t cidx = (size_t)row * ldc + colb;
                if constexpr (EPI == 0) {
                    us4 o; o.x = f2bf(v[0]); o.y = f2bf(v[1]); o.z = f2bf(v[2]); o.w = f2bf(v[3]);
                    *(us4*)(Cb + cidx) = o;
                } else if constexpr (EPI == 1) {
                    us4 o;
                    o.x = f2bf(v[0] > 0.f ? v[0] : 0.f); o.y = f2bf(v[1] > 0.f ? v[1] : 0.f);
                    o.z = f2bf(v[2] > 0.f ? v[2] : 0.f); o.w = f2bf(v[3] > 0.f ? v[3] : 0.f);
                    *(us4*)(Cb + cidx) = o;
                } else if constexpr (EPI == 2) {
                    float4 r = *(const float4*)(res + cidx);
                    float4 o = {v[0] + r.x, v[1] + r.y, v[2] + r.z, v[3] + r.w};
                    *(float4*)(Cf + cidx) = o;
                } else {                            // EPI == 4
                    float4 p = *(const float4*)(pe + (size_t)(row & 127) * 1024 + colb);
                    float4 o = {v[0] + p.x, v[1] + p.y, v[2] + p.z, v[3] + p.w};
                    *(float4*)(Cf + cidx) = o;
                    us4 ob;
                    ob.x = f2bf(o.x); ob.y = f2bf(o.y); ob.z = f2bf(o.z); ob.w = f2bf(o.w);
                    *(us4*)(Cb + cidx) = ob;
                }
            }
        }
    }
}

// ---------------- fused attention: one block per (b,h) ----------------
// S=128, D=64. QK^T -> causal softmax (fp32 math, bf16 storage) -> PV. 64KB LDS.
// Operand-swapped MFMA throughout: packed 8B S-writes and O-stores.
__global__ __launch_bounds__(256) void attn_fused(const bf16* __restrict__ qkv, bf16* __restrict__ obf)
{
    __shared__ __align__(16) char lds[65536];
    char* sQ  = lds;            // [128] rows x 128B, swizzled
    char* sK  = lds + 16384;    // [128] rows x 128B
    char* sS  = lds + 32768;    // [128] rows x 256B bf16 (scores, then P)
    char* sVT = lds;            // [64] rows x 256B (V transposed), overlaps sQ

    const int t = threadIdx.x, w = t >> 6, la = t & 63;
    const int b = blockIdx.x >> 4, h = blockIdx.x & 15;
    const size_t base = (size_t)b * 128 * 3072 + (size_t)h * 64;

    // phase 1: stage Q, K (swizzled via pre-swizzled source)
#pragma unroll
    for (int i = 0; i < 4; ++i) {
        int c = i * 256 + w * 64 + la;
        int r = c >> 3;
        int bc = ((c & 7) * 16) ^ ((r & 7) << 4);
        gload_lds16(qkv + base + (size_t)r * 3072 + (bc >> 1),
                    sQ + (size_t)(i * 256 + w * 64) * 16);
        gload_lds16(qkv + base + 1024 + (size_t)r * 3072 + (bc >> 1),
                    sK + (size_t)(i * 256 + w * 64) * 16);
    }
    __syncthreads();

    // phase 2: S = Q K^T * 0.125 (swapped mfma -> thread holds S[q][kb..kb+3])
    const int wm = (w >> 1) * 64, wn = (w & 1) * 64;
    facc4 zero4 = {0.f, 0.f, 0.f, 0.f};
    {
        facc4 acc[4][4];
#pragma unroll
        for (int mi = 0; mi < 4; ++mi)
#pragma unroll
            for (int ni = 0; ni < 4; ++ni) acc[mi][ni] = zero4;
#pragma unroll
        for (int ks = 0; ks < 2; ++ks) {
            bfrag8 af[4], bfv[4];
            const int koffb = (ks * 32 + (la >> 4) * 8) * 2;
#pragma unroll
            for (int i = 0; i < 4; ++i) {
                int rowa = wm + i * 16 + (la & 15);
                af[i] = *(const bfrag8*)(sQ + rowa * 128 + (koffb ^ ((rowa & 7) << 4)));
                int rowb = wn + i * 16 + (la & 15);
                bfv[i] = *(const bfrag8*)(sK + rowb * 128 + (koffb ^ ((rowb & 7) << 4)));
            }
#pragma unroll
            for (int mi = 0; mi < 4; ++mi)
#pragma unroll
                for (int ni = 0; ni < 4; ++ni)
                    acc[mi][ni] = __builtin_amdgcn_mfma_f32_16x16x32_bf16(bfv[ni], af[mi], acc[mi][ni], 0, 0, 0);
        }
#pragma unroll
        for (int mi = 0; mi < 4; ++mi) {
            int q = wm + mi * 16 + (la & 15);
#pragma unroll
            for (int ni = 0; ni < 4; ++ni) {
                int kb = wn + ni * 16 + (la >> 4) * 4;
                us4 sv;
                sv.x = f2bf(acc[mi][ni][0] * 0.125f); sv.y = f2bf(acc[mi][ni][1] * 0.125f);
                sv.z = f2bf(acc[mi][ni][2] * 0.125f); sv.w = f2bf(acc[mi][ni][3] * 0.125f);
                *(us4*)(sS + q * 256 + ((2 * kb) ^ ((q & 7) << 4))) = sv;
            }
        }
    }
    __syncthreads();

    // phase 3a: stage V transposed into sVT (sQ space, free now)
#pragma unroll
    for (int i = 0; i < 4; ++i) {
        int c = i * 256 + t;
        int r = c >> 3;             // key index s'
        int d0 = (c & 7) * 8;
        bfrag8 vv = *(const bfrag8*)(qkv + base + 2048 + (size_t)r * 3072 + d0);
#pragma unroll
        for (int j = 0; j < 8; ++j) {
            int d = d0 + j;
            *(short*)(sVT + d * 256 + ((2 * r) ^ ((d & 7) << 4))) = vv[j];
        }
    }
    // phase 3b: causal softmax, in place on sS (wave w owns rows w*32..w*32+31)
    for (int ri = 0; ri < 32; ++ri) {
        int r = w * 32 + ri;
        int c1 = la, c2 = la + 64;
        float v1 = (c1 <= r) ? __bfloat162float(*(const bf16*)(sS + r * 256 + ((2 * c1) ^ ((r & 7) << 4)))) : -1e30f;
        float v2 = (c2 <= r) ? __bfloat162float(*(const bf16*)(sS + r * 256 + ((2 * c2) ^ ((r & 7) << 4)))) : -1e30f;
        float mx = fmaxf(v1, v2);
#pragma unroll
        for (int off = 32; off; off >>= 1) mx = fmaxf(mx, __shfl_xor(mx, off));
        float e1 = (c1 <= r) ? __expf(v1 - mx) : 0.f;
        float e2 = (c2 <= r) ? __expf(v2 - mx) : 0.f;
        float sm = e1 + e2;
#pragma unroll
        for (int off = 32; off; off >>= 1) sm += __shfl_xor(sm, off);
        float inv = 1.f / sm;
        *(bf16*)(sS + r * 256 + ((2 * c1) ^ ((r & 7) << 4))) = __float2bfloat16(e1 * inv);
        *(bf16*)(sS + r * 256 + ((2 * c2) ^ ((r & 7) << 4))) = __float2bfloat16(e2 * inv);
    }
    __syncthreads();

    // phase 4: O = P V  (wave tile 64M x 32N, K=128; swapped mfma -> packed O stores)
    const int wm2 = (w >> 1) * 64, wn2 = (w & 1) * 32;
    facc4 a2[4][2];
#pragma unroll
    for (int mi = 0; mi < 4; ++mi) { a2[mi][0] = zero4; a2[mi][1] = zero4; }
#pragma unroll
    for (int ks = 0; ks < 4; ++ks) {
        bfrag8 pa[4], vb[2];
        const int koffb = (ks * 32 + (la >> 4) * 8) * 2;
#pragma unroll
        for (int mi = 0; mi < 4; ++mi) {
            int rowa = wm2 + mi * 16 + (la & 15);
            pa[mi] = *(const bfrag8*)(sS + rowa * 256 + (koffb ^ ((rowa & 7) << 4)));
        }
#pragma unroll
        for (int ni = 0; ni < 2; ++ni) {
            int rowb = wn2 + ni * 16 + (la & 15);
            vb[ni] = *(const bfrag8*)(sVT + rowb * 256 + (koffb ^ ((rowb & 7) << 4)));
        }
#pragma unroll
        for (int mi = 0; mi < 4; ++mi)
#pragma unroll
            for (int ni = 0; ni < 2; ++ni)
                a2[mi][ni] = __builtin_amdgcn_mfma_f32_16x16x32_bf16(vb[ni], pa[mi], a2[mi][ni], 0, 0, 0);
    }
#pragma unroll
    for (int mi = 0; mi < 4; ++mi) {
        int s = wm2 + mi * 16 + (la & 15);
#pragma unroll
        for (int ni = 0; ni < 2; ++ni) {
            int db = wn2 + ni * 16 + (la >> 4) * 4;
            us4 ov;
            ov.x = f2bf(a2[mi][ni][0]); ov.y = f2bf(a2[mi][ni][1]);
            ov.z = f2bf(a2[mi][ni][2]); ov.w = f2bf(a2[mi][ni][3]);
            *(us4*)(obf + ((size_t)(b * 128 + s)) * 1024 + h * 64 + db) = ov;
        }
    }
}

// ---------------- LayerNorm (one block per row of 1024) ----------------
__global__ __launch_bounds__(256) void ln_kernel(const float* __restrict__ in, const float* __restrict__ g,
                                                 const float* __restrict__ be,
                                                 float* __restrict__ outf, bf16* __restrict__ outb)
{
    const int row = blockIdx.x, t = threadIdx.x;
    const float* x = in + (size_t)row * 1024;
    float4 v = *(const float4*)(x + t * 4);
    float s = v.x + v.y + v.z + v.w;
    float q = v.x * v.x + v.y * v.y + v.z * v.z + v.w * v.w;
#pragma unroll
    for (int off = 32; off; off >>= 1) {
        s += __shfl_xor(s, off);
        q += __shfl_xor(q, off);
    }
    __shared__ float ssum[4], sqs[4];
    if ((t & 63) == 0) { ssum[t >> 6] = s; sqs[t >> 6] = q; }
    __syncthreads();
    s = ssum[0] + ssum[1] + ssum[2] + ssum[3];
    q = sqs[0] + sqs[1] + sqs[2] + sqs[3];
    float mean = s * (1.f / 1024.f);
    float var = q * (1.f / 1024.f) - mean * mean;
    float rstd = rsqrtf(var + 1e-5f);
    float4 gv = *(const float4*)(g + t * 4);
    float4 bv = *(const float4*)(be + t * 4);
    size_t o = (size_t)row * 1024 + t * 4;
    float o0 = (v.x - mean) * rstd * gv.x + bv.x;
    float o1 = (v.y - mean) * rstd * gv.y + bv.y;
    float o2 = (v.z - mean) * rstd * gv.z + bv.z;
    float o3 = (v.w - mean) * rstd * gv.w + bv.w;
    float4 of = {o0, o1, o2, o3};
    *(float4*)(outf + o) = of;
    us4 obv; obv.x = f2bf(o0); obv.y = f2bf(o1); obv.z = f2bf(o2); obv.w = f2bf(o3);
    *(us4*)(outb + o) = obv;
}

// ---------------- MDN finalize / scatter ----------------
__global__ void finalize_kernel(const float* __restrict__ hout, float* __restrict__ out) {
    const size_t O_PI_M = 0, O_MU_M = 32512, O_VAR_M = 552704, O_PI_V = 1072896,
                 O_MU_V = 1105408, O_VAR_V = 1625600, O_MASK = 2145792;
    int rm = blockIdx.x;                    // b*127+m, 4064 rows
    const float* hrow = hout + (size_t)rm * 529;
    int t = threadIdx.x;
    if (t < 128) {
        out[O_MU_M  + (size_t)rm * 128 + t] = hrow[9 + t];
        out[O_VAR_M + (size_t)rm * 128 + t] = expf(hrow[137 + t]);
        out[O_MU_V  + (size_t)rm * 128 + t] = hrow[273 + t];
        out[O_VAR_V + (size_t)rm * 128 + t] = expf(hrow[401 + t]);
    } else if (t == 128) {
        out[O_MASK + rm] = hrow[0];
    } else if (t == 129 || t == 130) {
        int boff = (t == 129) ? 1 : 265;
        size_t oo = ((t == 129) ? O_PI_M : O_PI_V) + (size_t)rm * 8;
        float v[8], mx = -1e30f;
#pragma unroll
        for (int j = 0; j < 8; ++j) { v[j] = hrow[boff + j]; mx = fmaxf(mx, v[j]); }
        float sm = 0.f;
#pragma unroll
        for (int j = 0; j < 8; ++j) { v[j] = expf(v[j] - mx); sm += v[j]; }
        float inv = 1.f / sm;
#pragma unroll
        for (int j = 0; j < 8; ++j) out[oo + j] = v[j] * inv;
    }
}

// ---------------- launcher ----------------
extern "C" void kernel_launch(void* const* d_in, const int* in_sizes, int n_in,
                              void* d_out, int out_size, void* d_ws, size_t ws_size,
                              hipStream_t stream) {
    (void)in_sizes; (void)n_in; (void)out_size; (void)ws_size;
    const float* input   = (const float*)d_in[0];
    const float* targets = (const float*)d_in[1];
    const float* W_emb   = (const float*)d_in[2];
    const float* b_emb   = (const float*)d_in[3];
    const float* sos     = (const float*)d_in[4];
    const float* Wqkv    = (const float*)d_in[5];
    const float* bqkv    = (const float*)d_in[6];
    const float* Wo      = (const float*)d_in[7];
    const float* bo      = (const float*)d_in[8];
    const float* W1      = (const float*)d_in[9];
    const float* b1      = (const float*)d_in[10];
    const float* W2      = (const float*)d_in[11];
    const float* b2      = (const float*)d_in[12];
    const float* g1      = (const float*)d_in[13];
    const float* be1     = (const float*)d_in[14];
    const float* g2      = (const float*)d_in[15];
    const float* be2     = (const float*)d_in[16];
    const float* Wm      = (const float*)d_in[17];
    const float* bm      = (const float*)d_in[18];
    const float* Wpi_m   = (const float*)d_in[19];
    const float* bpi_m   = (const float*)d_in[20];
    const float* Wmu_m   = (const float*)d_in[21];
    const float* bmu_m   = (const float*)d_in[22];
    const float* Wsg_m   = (const float*)d_in[23];
    const float* bsg_m   = (const float*)d_in[24];
    const float* Wpi_v   = (const float*)d_in[25];
    const float* bpi_v   = (const float*)d_in[26];
    const float* Wmu_v   = (const float*)d_in[27];
    const float* bmu_v   = (const float*)d_in[28];
    const float* Wsg_v   = (const float*)d_in[29];
    const float* bsg_v   = (const float*)d_in[30];
    float* out = (float*)d_out;

    char* ws = (char*)d_ws;                            // ~167 MB total
    float* pe      = (float*)(ws + 0);                 // 0.5 MB
    bf16*  xin     = (bf16*)(ws + 524288);             // 4.72 MB
    bf16*  wemb    = (bf16*)(ws + 5242880);            // 1.18 MB
    bf16*  whead   = (bf16*)(ws + 6422528);            // 1.31 MB (640 rows)
    float* bhead   = (float*)(ws + 7733248);           // 2.5 KB
    float* xf      = (float*)(ws + 7735808);           // 16.8 MB
    bf16*  xb      = (bf16*)(ws + 24513024);           // 8.4 MB
    bf16*  qkvb    = (bf16*)(ws + 32901632);           // 25.2 MB
    bf16*  ob      = (bf16*)(ws + 58067456);           // 8.4 MB (attn out, reused as FF hidden)
    float* tmp     = (float*)(ws + 66456064);          // 16.8 MB
    bf16*  wqb_all = (bf16*)(ws + 83233280);           // 37.7 MB (6 layers)
    bf16*  wob_all = (bf16*)(ws + 120982016);          // 12.6 MB
    bf16*  w1b_all = (bf16*)(ws + 133564928);          // 12.6 MB
    bf16*  w2b_all = (bf16*)(ws + 146147840);          // 12.6 MB
    float* hout    = (float*)(ws + 158730752);         // 8.6 MB

    prep_kernel<<<6272, 256, 0, stream>>>(input, targets, sos, W_emb,
                                          Wm, Wpi_m, Wmu_m, Wsg_m, Wpi_v, Wmu_v, Wsg_v,
                                          bm, bpi_m, bmu_m, bsg_m, bpi_v, bmu_v, bsg_v,
                                          pe, xin, wemb, whead, bhead);
    cvt_all_kernel<<<1152, 256, 0, stream>>>(Wqkv, Wo, W1, W2, wqb_all, wob_all, w1b_all, w2b_all);
    // x = XIN @ Wemb^T + b + pe   -> xf (f32) + xb (bf16)
    gemm_bt<4, 1><<<dim3(8, 32, 1), 256, 0, stream>>>(xin, wemb, xf, xb, b_emb, nullptr, pe,
                                                      4096, 1024, 576, 576, 576, 1024, 0, 0);
    for (int l = 0; l < 6; ++l) {
        const bf16* wqb = wqb_all + (size_t)l * 3145728;
        const bf16* wob = wob_all + (size_t)l * 1048576;
        const bf16* w1b = w1b_all + (size_t)l * 1048576;
        const bf16* w2b = w2b_all + (size_t)l * 1048576;
        // qkv = x @ Wqkv^T + b  (bf16 out) -- 768 blocks, single-buffer, 3 blocks/CU
        gemm_bt<0, 0><<<dim3(24, 32, 1), 256, 0, stream>>>(xb, wqb, nullptr, qkvb, bqkv + l * 3072,
                                                           nullptr, nullptr, 4096, 3072, 1024, 1024, 1024, 3072, 0, 0);
        attn_fused<<<512, 256, 0, stream>>>(qkvb, ob);
        // tmp = x + o @ Wo^T + bo -- 256 blocks, dbuf prefetch
        gemm_bt<2, 1><<<dim3(8, 32, 1), 256, 0, stream>>>(ob, wob, tmp, nullptr, bo + l * 1024,
                                                          xf, nullptr, 4096, 1024, 1024, 1024, 1024, 1024, 0, 0);
        ln_kernel<<<4096, 256, 0, stream>>>(tmp, g1 + l * 1024, be1 + l * 1024, xf, xb);
        // t1 = relu(x @ W1^T + b1) (bf16, reuse ob)
        gemm_bt<1, 1><<<dim3(8, 32, 1), 256, 0, stream>>>(xb, w1b, nullptr, ob, b1 + l * 1024,
                                                          nullptr, nullptr, 4096, 1024, 1024, 1024, 1024, 1024, 0, 0);
        // tmp = x + t1 @ W2^T + b2
        gemm_bt<2, 1><<<dim3(8, 32, 1), 256, 0, stream>>>(ob, w2b, tmp, nullptr, b2 + l * 1024,
                                                          xf, nullptr, 4096, 1024, 1024, 1024, 1024, 1024, 0, 0);
        ln_kernel<<<4096, 256, 0, stream>>>(tmp, g2 + l * 1024, be2 + l * 1024, xf, xb);
    }
    // heads: per-batch M=127 rows of x -> hout (B,127,529) -- 160 blocks, dbuf
    gemm_bt<3, 1><<<dim3(5, 1, 32), 256, 0, stream>>>(xb, whead, hout, nullptr, bhead, nullptr, nullptr,
                                                      127, 529, 1024, 1024, 1024, 529, 131072LL, 67183LL);
    finalize_kernel<<<4064, 256, 0, stream>>>(hout, out);
}

// Round 5
// 959.313 us; speedup vs baseline: 1.3695x; 1.0082x over previous
//
#include <hip/hip_runtime.h>
#include <hip/hip_bf16.h>

typedef __hip_bfloat16 bf16;
typedef __attribute__((ext_vector_type(8))) short bfrag8;   // 8 bf16 (4 VGPR) MFMA A/B frag
typedef __attribute__((ext_vector_type(4))) float facc4;    // MFMA C/D frag
typedef __attribute__((ext_vector_type(4))) unsigned short us4;
typedef __attribute__((ext_vector_type(8))) unsigned short us8;

#define AS1C const __attribute__((address_space(1))) void
#define AS3  __attribute__((address_space(3))) void

__device__ __forceinline__ void gload_lds16(const void* src, void* dst) {
    __builtin_amdgcn_global_load_lds((AS1C*)src, (AS3*)dst, 16, 0, 0);
}

__device__ __forceinline__ unsigned short f2bf(float f) {   // RNE, finite inputs
    unsigned u = __float_as_uint(f);
    unsigned r = u + 0x7FFFu + ((u >> 16) & 1u);
    return (unsigned short)(r >> 16);
}

// ------- merged prep+cvt kernel: pe | xin | wemb | whead | all weight cvt -------
// bid [0,512): pe | [512,4608): xin | [4608,5632): wemb | [5632,6272): whead
// bid [6272,10880): weight fp32->bf16, 768 blocks/layer (384 qkv, 128 wo/w1/w2),
//   each block = 1024 float4-PAIRS; thread converts 2 adjacent float4 -> one 16B us8 store.
__global__ void prep_cvt_kernel(const float* __restrict__ input, const float* __restrict__ targets,
                                const float* __restrict__ sos, const float* __restrict__ W_emb,
                                const float* __restrict__ Wm, const float* __restrict__ Wpi_m,
                                const float* __restrict__ Wmu_m, const float* __restrict__ Wsg_m,
                                const float* __restrict__ Wpi_v, const float* __restrict__ Wmu_v,
                                const float* __restrict__ Wsg_v,
                                const float* __restrict__ bm, const float* __restrict__ bpi_m,
                                const float* __restrict__ bmu_m, const float* __restrict__ bsg_m,
                                const float* __restrict__ bpi_v, const float* __restrict__ bmu_v,
                                const float* __restrict__ bsg_v,
                                const float* __restrict__ Wqkv, const float* __restrict__ Wo,
                                const float* __restrict__ W1, const float* __restrict__ W2,
                                float* __restrict__ pe, bf16* __restrict__ xin,
                                bf16* __restrict__ wemb, bf16* __restrict__ whead,
                                float* __restrict__ bhead,
                                bf16* __restrict__ wqb, bf16* __restrict__ wob,
                                bf16* __restrict__ w1b, bf16* __restrict__ w2b) {
    int bid = blockIdx.x;
    if (bid < 512) {                                     // pe [128][1024]
        int idx = bid * 256 + threadIdx.x;
        int s = idx >> 10, c = idx & 1023;
        int i = c >> 1;
        float div = expf(-9.210340371976184f * (float)(2 * i) * (1.f / 1024.f));
        float a = (float)s * div;
        pe[idx] = (c & 1) ? cosf(a) : sinf(a);
    } else if (bid < 512 + 4096) {                       // xin row (b*128+s), pad K->576
        int row = bid - 512;
        int b = row >> 7, s = row & 127;
        for (int c = threadIdx.x; c < 576; c += 256) {
            float v = 0.f;
            if (c < 512) v = input[b * 512 + c];
            else if (c < 545) {
                int j = c - 512;
                v = (s == 0) ? sos[j] : targets[((size_t)b * 127 + (s - 1)) * 33 + j];
            }
            xin[(size_t)row * 576 + c] = __float2bfloat16(v);
        }
    } else if (bid < 512 + 4096 + 1024) {                // wemb row, pad 545->576
        int row = bid - (512 + 4096);
        for (int c = threadIdx.x; c < 576; c += 256)
            wemb[(size_t)row * 576 + c] = __float2bfloat16(c < 545 ? W_emb[(size_t)row * 545 + c] : 0.f);
    } else if (bid < 6272) {                             // whead row (640 = 529 real + pad)
        int r = bid - (512 + 4096 + 1024);
        const float* wsrc = nullptr; const float* bsrc = nullptr; int off = 0;
        if (r == 0)        { wsrc = Wm;    bsrc = bm;    off = 0; }
        else if (r < 9)    { wsrc = Wpi_m; bsrc = bpi_m; off = r - 1; }
        else if (r < 137)  { wsrc = Wmu_m; bsrc = bmu_m; off = r - 9; }
        else if (r < 265)  { wsrc = Wsg_m; bsrc = bsg_m; off = r - 137; }
        else if (r < 273)  { wsrc = Wpi_v; bsrc = bpi_v; off = r - 265; }
        else if (r < 401)  { wsrc = Wmu_v; bsrc = bmu_v; off = r - 273; }
        else if (r < 529)  { wsrc = Wsg_v; bsrc = bsg_v; off = r - 401; }
        for (int c = threadIdx.x; c < 1024; c += 256)
            whead[(size_t)r * 1024 + c] = __float2bfloat16(wsrc ? wsrc[(size_t)off * 1024 + c] : 0.f);
        if (threadIdx.x == 0 && wsrc) bhead[r] = bsrc[off];
    } else {                                             // weight cvt
        int bid2 = bid - 6272;                           // [0,4608)
        int l = bid2 / 768;
        int s = bid2 - l * 768;
        const float* src; bf16* dst;
        if (s < 384)      { src = Wqkv + (size_t)l * 3145728; dst = wqb + (size_t)l * 3145728; }
        else if (s < 512) { src = Wo + (size_t)l * 1048576; dst = wob + (size_t)l * 1048576; s -= 384; }
        else if (s < 640) { src = W1 + (size_t)l * 1048576; dst = w1b + (size_t)l * 1048576; s -= 512; }
        else              { src = W2 + (size_t)l * 1048576; dst = w2b + (size_t)l * 1048576; s -= 640; }
        size_t pbase = (size_t)s * 1024 + threadIdx.x;
#pragma unroll
        for (int it = 0; it < 4; ++it) {
            size_t o = (pbase + it * 256) * 8;           // 8 floats per pair
            float4 v1 = *(const float4*)(src + o);
            float4 v2 = *(const float4*)(src + o + 4);
            us8 w8;
            w8[0] = f2bf(v1.x); w8[1] = f2bf(v1.y); w8[2] = f2bf(v1.z); w8[3] = f2bf(v1.w);
            w8[4] = f2bf(v2.x); w8[5] = f2bf(v2.y); w8[6] = f2bf(v2.z); w8[7] = f2bf(v2.w);
            *(us8*)(dst + o) = w8;
        }
    }
}

// ---------------- main GEMM: C[M,N] = A[M,K] @ B[N,K]^T (+epilogue) ----------------
// 128x128 tile, BK=64, 4 waves (each 64x64 of 16x16x32 bf16 MFMA).
// OPERAND-SWAPPED MFMA: acc = mfma(B_frag, A_frag) computes C^T fragments, so each
// thread holds row = lane&15 (fixed) and 4 CONSECUTIVE cols (lane>>4)*4+j -> all
// epilogue stores vectorize (us4 8B bf16 / float4 16B fp32) and bias/res/pe load float4.
// DBUF=1: double-buffered prefetch for grid-limited (<=256-block) launches.
// DBUF=0: single-buffer, 3 blocks/CU (cross-block overlap regime) for QKV.
// EPI: 0 bias->bf16 | 1 bias+relu->bf16 | 2 bias+res->f32 | 3 bias->f32 scalar (odd ldc) | 4 bias+pe->f32+bf16
template<int EPI, int DBUF>
__global__ __launch_bounds__(256, DBUF ? 2 : 3) void gemm_bt(
    const bf16* __restrict__ A, const bf16* __restrict__ Bw,
    float* __restrict__ Cf, bf16* __restrict__ Cb,
    const float* __restrict__ bias, const float* __restrict__ res, const float* __restrict__ pe,
    int M, int N, int K, int lda, int ldb, int ldc, long long Az, long long Cz)
{
    __shared__ __align__(16) bf16 sA[DBUF ? 2 : 1][128 * 64];
    __shared__ __align__(16) bf16 sB[DBUF ? 2 : 1][128 * 64];
    const int t = threadIdx.x;
    const int w = t >> 6, la = t & 63;
    const int wm = (w >> 1) * 64, wn = (w & 1) * 64;
    const int m0 = blockIdx.y * 128, n0 = blockIdx.x * 128;
    const int z = blockIdx.z;
    A += (long long)z * Az;

    const int c0 = w * 64 + la;
    facc4 zero4 = {0.f, 0.f, 0.f, 0.f};
    facc4 acc[4][4];
#pragma unroll
    for (int mi = 0; mi < 4; ++mi)
#pragma unroll
        for (int ni = 0; ni < 4; ++ni) acc[mi][ni] = zero4;

    auto stage = [&](int buf, int kt) {
#pragma unroll
        for (int i = 0; i < 4; ++i) {
            int c = i * 256 + c0;
            int r = c >> 3;
            int bc = ((c & 7) * 16) ^ ((r & 7) << 4);   // pre-swizzled source byte col
            gload_lds16(A + (size_t)(m0 + r) * lda + kt + (bc >> 1),
                        (char*)sA[buf] + (size_t)(i * 256 + c0) * 16);
            gload_lds16(Bw + (size_t)(n0 + r) * ldb + kt + (bc >> 1),
                        (char*)sB[buf] + (size_t)(i * 256 + c0) * 16);
        }
    };
    auto compute = [&](int buf) {
#pragma unroll
        for (int ks = 0; ks < 2; ++ks) {
            bfrag8 af[4], bfv[4];
            const int koffb = (ks * 32 + (la >> 4) * 8) * 2;
#pragma unroll
            for (int i = 0; i < 4; ++i) {
                int rowa = wm + i * 16 + (la & 15);
                af[i] = *(const bfrag8*)((const char*)sA[buf] + rowa * 128 + (koffb ^ ((rowa & 7) << 4)));
                int rowb = wn + i * 16 + (la & 15);
                bfv[i] = *(const bfrag8*)((const char*)sB[buf] + rowb * 128 + (koffb ^ ((rowb & 7) << 4)));
            }
#pragma unroll
            for (int mi = 0; mi < 4; ++mi)
#pragma unroll
                for (int ni = 0; ni < 4; ++ni)     // swapped operands -> C^T fragment
                    acc[mi][ni] = __builtin_amdgcn_mfma_f32_16x16x32_bf16(bfv[ni], af[mi], acc[mi][ni], 0, 0, 0);
        }
    };

    const int nk = K >> 6;
    if constexpr (DBUF) {
        stage(0, 0);
        __syncthreads();
        int cur = 0;
        for (int kt = 0; kt < nk; ++kt) {
            if (kt + 1 < nk) stage(cur ^ 1, (kt + 1) << 6);
            compute(cur);
            __syncthreads();        // drains stage(k+1) vmcnt; frees cur
            cur ^= 1;
        }
    } else {
        for (int kt = 0; kt < nk; ++kt) {
            stage(0, kt << 6);
            __syncthreads();
            compute(0);
            __syncthreads();
        }
    }
    // epilogue: thread holds C[row][colb..colb+3]
#pragma unroll
    for (int mi = 0; mi < 4; ++mi) {
        int row = m0 + wm + mi * 16 + (la & 15);
#pragma unroll
        for (int ni = 0; ni < 4; ++ni) {
            int colb = n0 + wn + ni * 16 + (la >> 4) * 4;
            if constexpr (EPI == 3) {               // scalar path (odd ldc / edge guards)
                if (row >= M) continue;
#pragma unroll
                for (int j = 0; j < 4; ++j) {
                    int col = colb + j;
                    if (col < N)
                        Cf[(size_t)z * Cz + (size_t)row * ldc + col] = acc[mi][ni][j] + bias[col];
                }
            } else {
                float4 bv = *(const float4*)(bias + colb);
                facc4 v = acc[mi][ni];
                v[0] += bv.x; v[1] += bv.y; v[2] += bv.z; v[3] += bv.w;
                size_t cidx = (size_t)row * ldc + colb;
                if constexpr (EPI == 0) {
                    us4 o; o.x = f2bf(v[0]); o.y = f2bf(v[1]); o.z = f2bf(v[2]); o.w = f2bf(v[3]);
                    *(us4*)(Cb + cidx) = o;
                } else if constexpr (EPI == 1) {
                    us4 o;
                    o.x = f2bf(v[0] > 0.f ? v[0] : 0.f); o.y = f2bf(v[1] > 0.f ? v[1] : 0.f);
                    o.z = f2bf(v[2] > 0.f ? v[2] : 0.f); o.w = f2bf(v[3] > 0.f ? v[3] : 0.f);
                    *(us4*)(Cb + cidx) = o;
                } else if constexpr (EPI == 2) {
                    float4 r = *(const float4*)(res + cidx);
                    float4 o = {v[0] + r.x, v[1] + r.y, v[2] + r.z, v[3] + r.w};
                    *(float4*)(Cf + cidx) = o;
                } else {                            // EPI == 4
                    float4 p = *(const float4*)(pe + (size_t)(row & 127) * 1024 + colb);
                    float4 o = {v[0] + p.x, v[1] + p.y, v[2] + p.z, v[3] + p.w};
                    *(float4*)(Cf + cidx) = o;
                    us4 ob;
                    ob.x = f2bf(o.x); ob.y = f2bf(o.y); ob.z = f2bf(o.z); ob.w = f2bf(o.w);
                    *(us4*)(Cb + cidx) = ob;
                }
            }
        }
    }
}

// ---------------- fused attention: one block per (b,h) ----------------
// S=128, D=64. QK^T -> causal softmax (fp32 math, bf16 storage) -> PV. 64KB LDS.
// Operand-swapped MFMA throughout: packed 8B S-writes and O-stores.
__global__ __launch_bounds__(256) void attn_fused(const bf16* __restrict__ qkv, bf16* __restrict__ obf)
{
    __shared__ __align__(16) char lds[65536];
    char* sQ  = lds;            // [128] rows x 128B, swizzled
    char* sK  = lds + 16384;    // [128] rows x 128B
    char* sS  = lds + 32768;    // [128] rows x 256B bf16 (scores, then P)
    char* sVT = lds;            // [64] rows x 256B (V transposed), overlaps sQ

    const int t = threadIdx.x, w = t >> 6, la = t & 63;
    const int b = blockIdx.x >> 4, h = blockIdx.x & 15;
    const size_t base = (size_t)b * 128 * 3072 + (size_t)h * 64;

    // phase 1: stage Q, K (swizzled via pre-swizzled source)
#pragma unroll
    for (int i = 0; i < 4; ++i) {
        int c = i * 256 + w * 64 + la;
        int r = c >> 3;
        int bc = ((c & 7) * 16) ^ ((r & 7) << 4);
        gload_lds16(qkv + base + (size_t)r * 3072 + (bc >> 1),
                    sQ + (size_t)(i * 256 + w * 64) * 16);
        gload_lds16(qkv + base + 1024 + (size_t)r * 3072 + (bc >> 1),
                    sK + (size_t)(i * 256 + w * 64) * 16);
    }
    __syncthreads();

    // phase 2: S = Q K^T * 0.125 (swapped mfma -> thread holds S[q][kb..kb+3])
    const int wm = (w >> 1) * 64, wn = (w & 1) * 64;
    facc4 zero4 = {0.f, 0.f, 0.f, 0.f};
    {
        facc4 acc[4][4];
#pragma unroll
        for (int mi = 0; mi < 4; ++mi)
#pragma unroll
            for (int ni = 0; ni < 4; ++ni) acc[mi][ni] = zero4;
#pragma unroll
        for (int ks = 0; ks < 2; ++ks) {
            bfrag8 af[4], bfv[4];
            const int koffb = (ks * 32 + (la >> 4) * 8) * 2;
#pragma unroll
            for (int i = 0; i < 4; ++i) {
                int rowa = wm + i * 16 + (la & 15);
                af[i] = *(const bfrag8*)(sQ + rowa * 128 + (koffb ^ ((rowa & 7) << 4)));
                int rowb = wn + i * 16 + (la & 15);
                bfv[i] = *(const bfrag8*)(sK + rowb * 128 + (koffb ^ ((rowb & 7) << 4)));
            }
#pragma unroll
            for (int mi = 0; mi < 4; ++mi)
#pragma unroll
                for (int ni = 0; ni < 4; ++ni)
                    acc[mi][ni] = __builtin_amdgcn_mfma_f32_16x16x32_bf16(bfv[ni], af[mi], acc[mi][ni], 0, 0, 0);
        }
#pragma unroll
        for (int mi = 0; mi < 4; ++mi) {
            int q = wm + mi * 16 + (la & 15);
#pragma unroll
            for (int ni = 0; ni < 4; ++ni) {
                int kb = wn + ni * 16 + (la >> 4) * 4;
                us4 sv;
                sv.x = f2bf(acc[mi][ni][0] * 0.125f); sv.y = f2bf(acc[mi][ni][1] * 0.125f);
                sv.z = f2bf(acc[mi][ni][2] * 0.125f); sv.w = f2bf(acc[mi][ni][3] * 0.125f);
                *(us4*)(sS + q * 256 + ((2 * kb) ^ ((q & 7) << 4))) = sv;
            }
        }
    }
    __syncthreads();

    // phase 3a: stage V transposed into sVT (sQ space, free now)
#pragma unroll
    for (int i = 0; i < 4; ++i) {
        int c = i * 256 + t;
        int r = c >> 3;             // key index s'
        int d0 = (c & 7) * 8;
        bfrag8 vv = *(const bfrag8*)(qkv + base + 2048 + (size_t)r * 3072 + d0);
#pragma unroll
        for (int j = 0; j < 8; ++j) {
            int d = d0 + j;
            *(short*)(sVT + d * 256 + ((2 * r) ^ ((d & 7) << 4))) = vv[j];
        }
    }
    // phase 3b: causal softmax, in place on sS (wave w owns rows w*32..w*32+31)
    for (int ri = 0; ri < 32; ++ri) {
        int r = w * 32 + ri;
        int c1 = la, c2 = la + 64;
        float v1 = (c1 <= r) ? __bfloat162float(*(const bf16*)(sS + r * 256 + ((2 * c1) ^ ((r & 7) << 4)))) : -1e30f;
        float v2 = (c2 <= r) ? __bfloat162float(*(const bf16*)(sS + r * 256 + ((2 * c2) ^ ((r & 7) << 4)))) : -1e30f;
        float mx = fmaxf(v1, v2);
#pragma unroll
        for (int off = 32; off; off >>= 1) mx = fmaxf(mx, __shfl_xor(mx, off));
        float e1 = (c1 <= r) ? __expf(v1 - mx) : 0.f;
        float e2 = (c2 <= r) ? __expf(v2 - mx) : 0.f;
        float sm = e1 + e2;
#pragma unroll
        for (int off = 32; off; off >>= 1) sm += __shfl_xor(sm, off);
        float inv = 1.f / sm;
        *(bf16*)(sS + r * 256 + ((2 * c1) ^ ((r & 7) << 4))) = __float2bfloat16(e1 * inv);
        *(bf16*)(sS + r * 256 + ((2 * c2) ^ ((r & 7) << 4))) = __float2bfloat16(e2 * inv);
    }
    __syncthreads();

    // phase 4: O = P V  (wave tile 64M x 32N, K=128; swapped mfma -> packed O stores)
    const int wm2 = (w >> 1) * 64, wn2 = (w & 1) * 32;
    facc4 a2[4][2];
#pragma unroll
    for (int mi = 0; mi < 4; ++mi) { a2[mi][0] = zero4; a2[mi][1] = zero4; }
#pragma unroll
    for (int ks = 0; ks < 4; ++ks) {
        bfrag8 pa[4], vb[2];
        const int koffb = (ks * 32 + (la >> 4) * 8) * 2;
#pragma unroll
        for (int mi = 0; mi < 4; ++mi) {
            int rowa = wm2 + mi * 16 + (la & 15);
            pa[mi] = *(const bfrag8*)(sS + rowa * 256 + (koffb ^ ((rowa & 7) << 4)));
        }
#pragma unroll
        for (int ni = 0; ni < 2; ++ni) {
            int rowb = wn2 + ni * 16 + (la & 15);
            vb[ni] = *(const bfrag8*)(sVT + rowb * 256 + (koffb ^ ((rowb & 7) << 4)));
        }
#pragma unroll
        for (int mi = 0; mi < 4; ++mi)
#pragma unroll
            for (int ni = 0; ni < 2; ++ni)
                a2[mi][ni] = __builtin_amdgcn_mfma_f32_16x16x32_bf16(vb[ni], pa[mi], a2[mi][ni], 0, 0, 0);
    }
#pragma unroll
    for (int mi = 0; mi < 4; ++mi) {
        int s = wm2 + mi * 16 + (la & 15);
#pragma unroll
        for (int ni = 0; ni < 2; ++ni) {
            int db = wn2 + ni * 16 + (la >> 4) * 4;
            us4 ov;
            ov.x = f2bf(a2[mi][ni][0]); ov.y = f2bf(a2[mi][ni][1]);
            ov.z = f2bf(a2[mi][ni][2]); ov.w = f2bf(a2[mi][ni][3]);
            *(us4*)(obf + ((size_t)(b * 128 + s)) * 1024 + h * 64 + db) = ov;
        }
    }
}

// ---------------- LayerNorm (one block per row of 1024) ----------------
__global__ __launch_bounds__(256) void ln_kernel(const float* __restrict__ in, const float* __restrict__ g,
                                                 const float* __restrict__ be,
                                                 float* __restrict__ outf, bf16* __restrict__ outb)
{
    const int row = blockIdx.x, t = threadIdx.x;
    const float* x = in + (size_t)row * 1024;
    float4 v = *(const float4*)(x + t * 4);
    float s = v.x + v.y + v.z + v.w;
    float q = v.x * v.x + v.y * v.y + v.z * v.z + v.w * v.w;
#pragma unroll
    for (int off = 32; off; off >>= 1) {
        s += __shfl_xor(s, off);
        q += __shfl_xor(q, off);
    }
    __shared__ float ssum[4], sqs[4];
    if ((t & 63) == 0) { ssum[t >> 6] = s; sqs[t >> 6] = q; }
    __syncthreads();
    s = ssum[0] + ssum[1] + ssum[2] + ssum[3];
    q = sqs[0] + sqs[1] + sqs[2] + sqs[3];
    float mean = s * (1.f / 1024.f);
    float var = q * (1.f / 1024.f) - mean * mean;
    float rstd = rsqrtf(var + 1e-5f);
    float4 gv = *(const float4*)(g + t * 4);
    float4 bv = *(const float4*)(be + t * 4);
    size_t o = (size_t)row * 1024 + t * 4;
    float o0 = (v.x - mean) * rstd * gv.x + bv.x;
    float o1 = (v.y - mean) * rstd * gv.y + bv.y;
    float o2 = (v.z - mean) * rstd * gv.z + bv.z;
    float o3 = (v.w - mean) * rstd * gv.w + bv.w;
    float4 of = {o0, o1, o2, o3};
    *(float4*)(outf + o) = of;
    us4 obv; obv.x = f2bf(o0); obv.y = f2bf(o1); obv.z = f2bf(o2); obv.w = f2bf(o3);
    *(us4*)(outb + o) = obv;
}

// ---------------- MDN finalize / scatter ----------------
__global__ void finalize_kernel(const float* __restrict__ hout, float* __restrict__ out) {
    const size_t O_PI_M = 0, O_MU_M = 32512, O_VAR_M = 552704, O_PI_V = 1072896,
                 O_MU_V = 1105408, O_VAR_V = 1625600, O_MASK = 2145792;
    int rm = blockIdx.x;                    // b*127+m, 4064 rows
    const float* hrow = hout + (size_t)rm * 529;
    int t = threadIdx.x;
    if (t < 128) {
        out[O_MU_M  + (size_t)rm * 128 + t] = hrow[9 + t];
        out[O_VAR_M + (size_t)rm * 128 + t] = expf(hrow[137 + t]);
        out[O_MU_V  + (size_t)rm * 128 + t] = hrow[273 + t];
        out[O_VAR_V + (size_t)rm * 128 + t] = expf(hrow[401 + t]);
    } else if (t == 128) {
        out[O_MASK + rm] = hrow[0];
    } else if (t == 129 || t == 130) {
        int boff = (t == 129) ? 1 : 265;
        size_t oo = ((t == 129) ? O_PI_M : O_PI_V) + (size_t)rm * 8;
        float v[8], mx = -1e30f;
#pragma unroll
        for (int j = 0; j < 8; ++j) { v[j] = hrow[boff + j]; mx = fmaxf(mx, v[j]); }
        float sm = 0.f;
#pragma unroll
        for (int j = 0; j < 8; ++j) { v[j] = expf(v[j] - mx); sm += v[j]; }
        float inv = 1.f / sm;
#pragma unroll
        for (int j = 0; j < 8; ++j) out[oo + j] = v[j] * inv;
    }
}

// ---------------- launcher ----------------
extern "C" void kernel_launch(void* const* d_in, const int* in_sizes, int n_in,
                              void* d_out, int out_size, void* d_ws, size_t ws_size,
                              hipStream_t stream) {
    (void)in_sizes; (void)n_in; (void)out_size; (void)ws_size;
    const float* input   = (const float*)d_in[0];
    const float* targets = (const float*)d_in[1];
    const float* W_emb   = (const float*)d_in[2];
    const float* b_emb   = (const float*)d_in[3];
    const float* sos     = (const float*)d_in[4];
    const float* Wqkv    = (const float*)d_in[5];
    const float* bqkv    = (const float*)d_in[6];
    const float* Wo      = (const float*)d_in[7];
    const float* bo      = (const float*)d_in[8];
    const float* W1      = (const float*)d_in[9];
    const float* b1      = (const float*)d_in[10];
    const float* W2      = (const float*)d_in[11];
    const float* b2      = (const float*)d_in[12];
    const float* g1      = (const float*)d_in[13];
    const float* be1     = (const float*)d_in[14];
    const float* g2      = (const float*)d_in[15];
    const float* be2     = (const float*)d_in[16];
    const float* Wm      = (const float*)d_in[17];
    const float* bm      = (const float*)d_in[18];
    const float* Wpi_m   = (const float*)d_in[19];
    const float* bpi_m   = (const float*)d_in[20];
    const float* Wmu_m   = (const float*)d_in[21];
    const float* bmu_m   = (const float*)d_in[22];
    const float* Wsg_m   = (const float*)d_in[23];
    const float* bsg_m   = (const float*)d_in[24];
    const float* Wpi_v   = (const float*)d_in[25];
    const float* bpi_v   = (const float*)d_in[26];
    const float* Wmu_v   = (const float*)d_in[27];
    const float* bmu_v   = (const float*)d_in[28];
    const float* Wsg_v   = (const float*)d_in[29];
    const float* bsg_v   = (const float*)d_in[30];
    float* out = (float*)d_out;

    char* ws = (char*)d_ws;                            // ~167 MB total
    float* pe      = (float*)(ws + 0);                 // 0.5 MB
    bf16*  xin     = (bf16*)(ws + 524288);             // 4.72 MB
    bf16*  wemb    = (bf16*)(ws + 5242880);            // 1.18 MB
    bf16*  whead   = (bf16*)(ws + 6422528);            // 1.31 MB (640 rows)
    float* bhead   = (float*)(ws + 7733248);           // 2.5 KB
    float* xf      = (float*)(ws + 7735808);           // 16.8 MB
    bf16*  xb      = (bf16*)(ws + 24513024);           // 8.4 MB
    bf16*  qkvb    = (bf16*)(ws + 32901632);           // 25.2 MB
    bf16*  ob      = (bf16*)(ws + 58067456);           // 8.4 MB (attn out, reused as FF hidden)
    float* tmp     = (float*)(ws + 66456064);          // 16.8 MB
    bf16*  wqb_all = (bf16*)(ws + 83233280);           // 37.7 MB (6 layers)
    bf16*  wob_all = (bf16*)(ws + 120982016);          // 12.6 MB
    bf16*  w1b_all = (bf16*)(ws + 133564928);          // 12.6 MB
    bf16*  w2b_all = (bf16*)(ws + 146147840);          // 12.6 MB
    float* hout    = (float*)(ws + 158730752);         // 8.6 MB

    prep_cvt_kernel<<<10880, 256, 0, stream>>>(input, targets, sos, W_emb,
                                               Wm, Wpi_m, Wmu_m, Wsg_m, Wpi_v, Wmu_v, Wsg_v,
                                               bm, bpi_m, bmu_m, bsg_m, bpi_v, bmu_v, bsg_v,
                                               Wqkv, Wo, W1, W2,
                                               pe, xin, wemb, whead, bhead,
                                               wqb_all, wob_all, w1b_all, w2b_all);
    // x = XIN @ Wemb^T + b + pe   -> xf (f32) + xb (bf16)
    gemm_bt<4, 1><<<dim3(8, 32, 1), 256, 0, stream>>>(xin, wemb, xf, xb, b_emb, nullptr, pe,
                                                      4096, 1024, 576, 576, 576, 1024, 0, 0);
    for (int l = 0; l < 6; ++l) {
        const bf16* wqb = wqb_all + (size_t)l * 3145728;
        const bf16* wob = wob_all + (size_t)l * 1048576;
        const bf16* w1b = w1b_all + (size_t)l * 1048576;
        const bf16* w2b = w2b_all + (size_t)l * 1048576;
        // qkv = x @ Wqkv^T + b  (bf16 out) -- 768 blocks, single-buffer, 3 blocks/CU
        gemm_bt<0, 0><<<dim3(24, 32, 1), 256, 0, stream>>>(xb, wqb, nullptr, qkvb, bqkv + l * 3072,
                                                           nullptr, nullptr, 4096, 3072, 1024, 1024, 1024, 3072, 0, 0);
        attn_fused<<<512, 256, 0, stream>>>(qkvb, ob);
        // tmp = x + o @ Wo^T + bo -- 256 blocks, dbuf prefetch
        gemm_bt<2, 1><<<dim3(8, 32, 1), 256, 0, stream>>>(ob, wob, tmp, nullptr, bo + l * 1024,
                                                          xf, nullptr, 4096, 1024, 1024, 1024, 1024, 1024, 0, 0);
        ln_kernel<<<4096, 256, 0, stream>>>(tmp, g1 + l * 1024, be1 + l * 1024, xf, xb);
        // t1 = relu(x @ W1^T + b1) (bf16, reuse ob)
        gemm_bt<1, 1><<<dim3(8, 32, 1), 256, 0, stream>>>(xb, w1b, nullptr, ob, b1 + l * 1024,
                                                          nullptr, nullptr, 4096, 1024, 1024, 1024, 1024, 1024, 0, 0);
        // tmp = x + t1 @ W2^T + b2
        gemm_bt<2, 1><<<dim3(8, 32, 1), 256, 0, stream>>>(ob, w2b, tmp, nullptr, b2 + l * 1024,
                                                          xf, nullptr, 4096, 1024, 1024, 1024, 1024, 1024, 0, 0);
        ln_kernel<<<4096, 256, 0, stream>>>(tmp, g2 + l * 1024, be2 + l * 1024, xf, xb);
    }
    // heads: per-batch M=127 rows of x -> hout (B,127,529) -- 160 blocks, dbuf
    gemm_bt<3, 1><<<dim3(5, 1, 32), 256, 0, stream>>>(xb, whead, hout, nullptr, bhead, nullptr, nullptr,
                                                      127, 529, 1024, 1024, 1024, 529, 131072LL, 67183LL);
    finalize_kernel<<<4064, 256, 0, stream>>>(hout, out);
}